// Round 8
// baseline (781.618 us; speedup 1.0000x reference)
//
#include <hip/hip_runtime.h>
#include <cstdint>
#include <cstddef>

typedef unsigned short u16;
typedef __bf16 bf16x8 __attribute__((ext_vector_type(8)));
typedef __bf16 bf16x2 __attribute__((ext_vector_type(2)));
typedef float f32x4 __attribute__((ext_vector_type(4)));
typedef float f32x16 __attribute__((ext_vector_type(16)));

#define B_   4
#define T_   2048
#define H_   1024
#define NH_  16
#define DH_  64
#define M_   (B_ * T_)      // 8192
#define KDIM 1024
// SCALE * log2(e): scores computed directly in log2 domain
#define QSCALE 0.18033688011112042f

#define BM 128
#define BN 128
#define BK 32

__device__ __forceinline__ u16 f2bf(float f) {
    unsigned u = __float_as_uint(f);
    unsigned r = (u + 0x7fffu + ((u >> 16) & 1u)) >> 16;  // RNE
    return (u16)r;
}

__device__ __forceinline__ unsigned packbf2(float a, float b) {
    bf16x2 v = { (__bf16)a, (__bf16)b };   // compiler emits v_cvt_pk_bf16_f32
    return __builtin_bit_cast(unsigned, v);
}

__device__ __forceinline__ float exp2_fast(float x) {
#if __has_builtin(__builtin_amdgcn_exp2f)
    return __builtin_amdgcn_exp2f(x);
#else
    return exp2f(x);
#endif
}

// in-place half-wave swap
__device__ __forceinline__ void plswap(unsigned &a, unsigned &b) {
#if __has_builtin(__builtin_amdgcn_permlane32_swap)
    auto r = __builtin_amdgcn_permlane32_swap(a, b, false, false);
    a = (unsigned)r[0]; b = (unsigned)r[1];
#else
    int hi = (threadIdx.x & 32);
    unsigned x = (unsigned)__shfl_xor((int)(hi ? b : a), 32);
    unsigned na = hi ? x : a;
    unsigned nb = hi ? b : x;
    a = na; b = nb;
#endif
}

__device__ __forceinline__ void gload16(const void* g, void* l) {
    __builtin_amdgcn_global_load_lds(
        (const __attribute__((address_space(1))) unsigned int*)g,
        (__attribute__((address_space(3))) unsigned int*)l,
        16, 0, 0);
}

__device__ __forceinline__ f32x16 mfma32(bf16x8 a, bf16x8 b, f32x16 c) {
    return __builtin_amdgcn_mfma_f32_32x32x16_bf16(a, b, c, 0, 0, 0);
}

// fused drain + barrier: ds_reads AND staged vmem both complete before cross
__device__ __forceinline__ void wait_barrier() {
    asm volatile("s_waitcnt vmcnt(0) lgkmcnt(0)\n\ts_barrier" ::: "memory");
}

// ---------------- fp32 -> bf16 converts (single launch, 6 jobs) ----------------
__global__ __launch_bounds__(256) void f2bf_hex(
    const float* s0, u16* d0, int n0, const float* s1, u16* d1, int n1,
    const float* s2, u16* d2, int n2, const float* s3, u16* d3, int n3,
    const float* s4, u16* d4, int n4j, const float* s5, u16* d5, int n5)
{
    const float* s; u16* d; int n;
    switch (blockIdx.y) {
        case 0: s = s0; d = d0; n = n0; break;
        case 1: s = s1; d = d1; n = n1; break;
        case 2: s = s2; d = d2; n = n2; break;
        case 3: s = s3; d = d3; n = n3; break;
        case 4: s = s4; d = d4; n = n4j; break;
        default: s = s5; d = d5; n = n5; break;
    }
    int i = blockIdx.x * blockDim.x + threadIdx.x;
    int stride = gridDim.x * blockDim.x;
    for (; i < n; i += stride) {
        float4 f = reinterpret_cast<const float4*>(s)[i];
        ushort4 o;
        o.x = f2bf(f.x); o.y = f2bf(f.y); o.z = f2bf(f.z); o.w = f2bf(f.w);
        reinterpret_cast<ushort4*>(d)[i] = o;
    }
}

// ---------------- 128x128 bf16 GEMM core  C = X * W^T ----------------
// Double-buffered K-loop: stage k+1 early, ONE drain+barrier per K-step.
__device__ __forceinline__ void gemm_core(
    const u16* __restrict__ X, const u16* __restrict__ W,
    const float* __restrict__ bias,
    u16* __restrict__ dst_bf, float* __restrict__ dst_f,
    float scale, int mode, int r0, int c0)
{
    __shared__ u16 lds[17408];
    char* const base = (char*)lds;

    const int tid = threadIdx.x;
    const int wid = tid >> 6;
    const int l15 = tid & 15;
    const int l4  = (tid & 63) >> 4;
    const int wr = wid >> 1, wc = wid & 1;

    const u16* gA = X + (size_t)(r0 + (tid >> 2)) * KDIM + (tid & 3) * 8;
    const u16* gB = W + (size_t)(c0 + (tid >> 2)) * KDIM + (tid & 3) * 8;

    f32x4 acc[4][4];
#pragma unroll
    for (int m = 0; m < 4; ++m)
#pragma unroll
        for (int n = 0; n < 4; ++n) acc[m][n] = (f32x4){0.f, 0.f, 0.f, 0.f};

    const int arow = wr * 64 + l15;
    const int brow = wc * 64 + l15;

#define STAGEG(p, kt) do { \
    const u16* pa_ = gA + (kt) * BK; \
    const u16* pb_ = gB + (kt) * BK; \
    char* dA_ = base + (p) * 16384 + wid * 1024; \
    char* dB_ = dA_ + 8192; \
    gload16(pa_, dA_); gload16(pa_ + 64 * KDIM, dA_ + 4096); \
    gload16(pb_, dB_); gload16(pb_ + 64 * KDIM, dB_ + 4096); } while (0)

    STAGEG(0, 0);
    wait_barrier();

    for (int kt = 0; kt < KDIM / BK; ++kt) {
        if (kt + 1 < KDIM / BK) STAGEG((kt + 1) & 1, kt + 1);
        const char* bufp = base + (kt & 1) * 16384;
        bf16x8 a[4], b[4];
#pragma unroll
        for (int m = 0; m < 4; ++m)
            a[m] = *(const bf16x8*)(bufp + (arow + m * 16) * 64 + l4 * 16);
#pragma unroll
        for (int n = 0; n < 4; ++n)
            b[n] = *(const bf16x8*)(bufp + 8192 + (brow + n * 16) * 64 + l4 * 16);
#pragma unroll
        for (int m = 0; m < 4; ++m)
#pragma unroll
            for (int n = 0; n < 4; ++n)
                acc[m][n] = __builtin_amdgcn_mfma_f32_16x16x32_bf16(a[m], b[n], acc[m][n], 0, 0, 0);
        wait_barrier();
    }
#undef STAGEG

    if (mode == 2) {
#pragma unroll
        for (int m = 0; m < 4; ++m)
#pragma unroll
            for (int n = 0; n < 4; ++n) {
                int cg = c0 + wc * 64 + n * 16 + l15;
                float bv = bias[cg];
                int rg = r0 + wr * 64 + m * 16 + l4 * 4;
#pragma unroll
                for (int j = 0; j < 4; ++j)
                    dst_f[(size_t)(rg + j) * H_ + cg] = acc[m][n][j] + bv;
            }
    } else if (mode == 0) {
        __syncthreads();
        u16 (*ldsR)[136] = (u16(*)[136])lds;
#pragma unroll
        for (int m = 0; m < 4; ++m)
#pragma unroll
            for (int n = 0; n < 4; ++n) {
                int cl = wc * 64 + n * 16 + l15;
                float bv = bias[c0 + cl];
                int rl = wr * 64 + m * 16 + l4 * 4;
#pragma unroll
                for (int j = 0; j < 4; ++j)
                    ldsR[rl + j][cl] = f2bf((acc[m][n][j] + bv) * scale);
            }
        __syncthreads();
        int b2 = r0 >> 11, tb = r0 & (T_ - 1);
#pragma unroll
        for (int it = 0; it < 8; ++it) {
            int id = tid + it * 256;
            int row = id >> 4;
            int ch = id & 15;
            int head = (c0 >> 6) + (ch >> 3);
            int d0 = (ch & 7) * 8;
            uint4 v = *(const uint4*)&ldsR[row][ch * 8];
            *(uint4*)&dst_bf[(((size_t)(b2 * NH_ + head) * T_ + tb + row) << 6) + d0] = v;
        }
    } else {
        __syncthreads();
        u16 (*ldsT)[136] = (u16(*)[136])lds;
#pragma unroll
        for (int m = 0; m < 4; ++m)
#pragma unroll
            for (int n = 0; n < 4; ++n) {
                int cl = wc * 64 + n * 16 + l15;
                float bv = bias[c0 + cl];
                int rl = wr * 64 + m * 16 + l4 * 4;
#pragma unroll
                for (int j = 0; j < 4; ++j)
                    ldsT[cl][rl + j] = f2bf(acc[m][n][j] + bv);
            }
        __syncthreads();
        int b = r0 >> 11, tb = r0 & (T_ - 1);
#pragma unroll
        for (int it = 0; it < 8; ++it) {
            int chunk = tid + it * 256;
            int cl = chunk >> 4;
            int r8 = (chunk & 15) << 3;
            int cg = c0 + cl;
            int head = cg >> 6, d = cg & 63;
            uint4 v = *(const uint4*)&ldsT[cl][r8];
            *(uint4*)&dst_bf[((size_t)((b * NH_ + head) * DH_ + d) * T_) + tb + r8] = v;
        }
    }
}

// Fused QKV projection: grid (24,64). bx 0-7: Q, 8-15: K, 16-23: V.
__global__ __launch_bounds__(256) void gemm_qkv(
    const u16* __restrict__ qbf, const u16* __restrict__ vbf,
    const u16* __restrict__ Wqb, const u16* __restrict__ Wkb, const u16* __restrict__ Wvb,
    const float* __restrict__ bq, const float* __restrict__ bk, const float* __restrict__ bv,
    u16* __restrict__ Qd, u16* __restrict__ Kd, u16* __restrict__ Vtd)
{
    const int orig = blockIdx.y * 24 + blockIdx.x;
    const int swz = (orig & 7) * 192 + (orig >> 3);
    const int bx = swz % 24;
    const int by = swz / 24;
    const int seg = bx >> 3;
    const int r0 = by * BM;
    const int c0 = (bx & 7) * BN;

    if (seg == 0)
        gemm_core(qbf, Wqb, bq, Qd, nullptr, QSCALE, 0, r0, c0);
    else if (seg == 1)
        gemm_core(vbf, Wkb, bk, Kd, nullptr, 1.0f, 0, r0, c0);
    else
        gemm_core(vbf, Wvb, bv, Vtd, nullptr, 1.0f, 1, r0, c0);
}

// Output projection: grid (8,64). XCD swizzle chunk=64.
__global__ __launch_bounds__(256) void gemm_out(
    const u16* __restrict__ AO, const u16* __restrict__ Wob,
    const float* __restrict__ bo, float* __restrict__ out)
{
    const int orig = blockIdx.y * 8 + blockIdx.x;
    const int swz = (orig & 7) * 64 + (orig >> 3);
    const int bx = swz & 7;
    const int by = swz >> 3;
    gemm_core(AO, Wob, bo, nullptr, out, 1.0f, 2, by * BM, bx * BN);
}

#define KVB 64

// ================== KV-split partial attention ==================
// Each block: 256 q rows x HALF the kv range (16 tiles). Grid (16,64) = 1024
// blocks = 4/CU = 4 waves/SIMD (2x the single-kernel occupancy).
// Writes UNNORMALIZED O-partials f32 [h][bn][d][q] + L-partials [h][bn][q].
// Exact: no-max softmax => partials over disjoint kv ranges are plain sums.
__global__ __launch_bounds__(256, 4) void attnP(
    const u16* __restrict__ Q, const u16* __restrict__ K,
    const u16* __restrict__ Vt,
    float* __restrict__ OpA, float* __restrict__ OpB,
    float* __restrict__ LpA, float* __restrict__ LpB)
{
    __shared__ u16 lds[16384];   // 32KB: K0|V0|K1|V1, 8KB each
    char* const base = (char*)lds;

    const int tid = threadIdx.x;
    const int wid = tid >> 6;
    const int lane = tid & 63;
    const int l31 = lane & 31;
    const int hi = lane >> 5;

    // XCD swizzle: nwg=1024, chunk=128 => 8 whole heads per XCD
    const int orig = blockIdx.y * 16 + blockIdx.x;
    const int swz = (orig & 7) * 128 + (orig >> 3);
    const int bn = swz >> 4;
    const int rest = swz & 15;
    const int h = rest >> 3;                       // kv half
    const int q0w = (rest & 7) * 256 + wid * 64;   // wave's q base
    const int kv0 = h * (T_ / 2);

    const u16* Qb = Q + ((size_t)bn * T_ + q0w + l31) * DH_;
    const u16* Kb = K + (size_t)bn * T_ * DH_;
    const u16* Vb = Vt + (size_t)bn * DH_ * T_;

    bf16x8 qfa[4], qfb[4];
#pragma unroll
    for (int c = 0; c < 4; ++c) {
        qfa[c] = *(const bf16x8*)(Qb + c * 16 + hi * 8);
        qfb[c] = *(const bf16x8*)(Qb + 32 * DH_ + c * 16 + hi * 8);
    }

    f32x16 accO00, accO01, accO10, accO11;
#pragma unroll
    for (int r = 0; r < 16; ++r) {
        accO00[r] = 0.f; accO01[r] = 0.f;
        accO10[r] = 0.f; accO11[r] = 0.f;
    }
    float la = 0.f, lb = 0.f;

    const int srow = tid >> 3;
    const int scsw = (tid & 7) ^ (srow & 7);
    const int rowsw = l31 & 7;

    const u16* kSrc = Kb + (size_t)(kv0 + srow) * DH_ + scsw * 8;
    const u16* vSrc = Vb + (size_t)srow * T_ + kv0 + scsw * 8;

#define STAGE(dK, dV) do { \
    gload16(kSrc,            (dK) + tid * 16); \
    gload16(kSrc + 32 * DH_, (dK) + 4096 + tid * 16); \
    gload16(vSrc,            (dV) + tid * 16); \
    gload16(vSrc + 32 * T_,  (dV) + 4096 + tid * 16); \
    kSrc += KVB * DH_; vSrc += KVB; } while (0)

    char* const kb0 = base;
    char* const vb0 = base + 8192;
    char* const kb1 = base + 16384;
    char* const vb1 = base + 24576;

    auto process = [&](const char* kc, const char* vc) {
        f32x16 sA0, sA1, sB0, sB1;
#pragma unroll
        for (int r = 0; r < 16; ++r) { sA0[r] = 0.f; sA1[r] = 0.f; sB0[r] = 0.f; sB1[r] = 0.f; }
        __builtin_amdgcn_s_setprio(1);
#pragma unroll
        for (int c = 0; c < 4; ++c) {
            const int c16 = ((2 * c + hi) ^ rowsw) * 16;
            bf16x8 k0 = *(const bf16x8*)(kc + l31 * 128 + c16);
            bf16x8 k1 = *(const bf16x8*)(kc + 4096 + l31 * 128 + c16);
            sA0 = mfma32(k0, qfa[c], sA0);
            sA1 = mfma32(k1, qfa[c], sA1);
            sB0 = mfma32(k0, qfb[c], sB0);
            sB1 = mfma32(k1, qfb[c], sB1);
        }
        __builtin_amdgcn_s_setprio(0);

#pragma unroll
        for (int r = 0; r < 16; ++r) {
            sA0[r] = exp2_fast(sA0[r]);
            sA1[r] = exp2_fast(sA1[r]);
            sB0[r] = exp2_fast(sB0[r]);
            sB1[r] = exp2_fast(sB1[r]);
        }
        float ta = 0.f, tb2 = 0.f;
#pragma unroll
        for (int r = 0; r < 16; ++r) {
            ta  += sA0[r] + sA1[r];
            tb2 += sB0[r] + sB1[r];
        }
        la += ta; lb += tb2;

        unsigned w0a[8], w1a[8], w0b[8], w1b[8];
#pragma unroll
        for (int k2 = 0; k2 < 8; ++k2) {
            w0a[k2] = packbf2(sA0[2 * k2], sA0[2 * k2 + 1]);
            w1a[k2] = packbf2(sA1[2 * k2], sA1[2 * k2 + 1]);
            w0b[k2] = packbf2(sB0[2 * k2], sB0[2 * k2 + 1]);
            w1b[k2] = packbf2(sB1[2 * k2], sB1[2 * k2 + 1]);
        }
        plswap(w0a[0], w0a[2]); plswap(w0a[1], w0a[3]);
        plswap(w0a[4], w0a[6]); plswap(w0a[5], w0a[7]);
        plswap(w1a[0], w1a[2]); plswap(w1a[1], w1a[3]);
        plswap(w1a[4], w1a[6]); plswap(w1a[5], w1a[7]);
        plswap(w0b[0], w0b[2]); plswap(w0b[1], w0b[3]);
        plswap(w0b[4], w0b[6]); plswap(w0b[5], w0b[7]);
        plswap(w1b[0], w1b[2]); plswap(w1b[1], w1b[3]);
        plswap(w1b[4], w1b[6]); plswap(w1b[5], w1b[7]);

        __builtin_amdgcn_s_setprio(1);
#pragma unroll
        for (int ks = 0; ks < 4; ++ks) {
            union { unsigned w[4]; bf16x8 v; } pa, pb;
            const unsigned* sa_ = (ks < 2) ? w0a : w1a;
            const unsigned* sb_ = (ks < 2) ? w0b : w1b;
            const int o = (ks & 1) * 4;
            pa.w[0] = sa_[o + 0]; pa.w[1] = sa_[o + 1];
            pa.w[2] = sa_[o + 2]; pa.w[3] = sa_[o + 3];
            pb.w[0] = sb_[o + 0]; pb.w[1] = sb_[o + 1];
            pb.w[2] = sb_[o + 2]; pb.w[3] = sb_[o + 3];
            const int c16 = ((2 * ks + hi) ^ rowsw) * 16;
            bf16x8 v0f = *(const bf16x8*)(vc + l31 * 128 + c16);
            bf16x8 v1f = *(const bf16x8*)(vc + 4096 + l31 * 128 + c16);
            accO00 = mfma32(v0f, pa.v, accO00);
            accO01 = mfma32(v1f, pa.v, accO01);
            accO10 = mfma32(v0f, pb.v, accO10);
            accO11 = mfma32(v1f, pb.v, accO11);
        }
        __builtin_amdgcn_s_setprio(0);
    };

    STAGE(kb0, vb0);
    __syncthreads();

    const int NT = (T_ / 2) / KVB;   // 16
    for (int it = 0; it < NT; it += 2) {
        STAGE(kb1, vb1);
        process(kb0, vb0);
        __syncthreads();
        if (it + 2 < NT) STAGE(kb0, vb0);
        process(kb1, vb1);
        __syncthreads();
    }

    // ---- epilogue: store unnormalized partials, f32, q-contiguous ----
    la += __shfl_xor(la, 32);
    lb += __shfl_xor(lb, 32);

    float* Ob = (h ? OpB : OpA) + (size_t)bn * 64 * T_;
    float* Lb2 = (h ? LpB : LpA) + (size_t)bn * T_;
#pragma unroll
    for (int n = 0; n < 2; ++n)
#pragma unroll
        for (int r = 0; r < 16; ++r) {
            int d = n * 32 + (r & 3) + 8 * (r >> 2) + 4 * hi;
            Ob[(size_t)d * T_ + q0w + l31]      = (n == 0 ? accO00[r] : accO01[r]);
            Ob[(size_t)d * T_ + q0w + 32 + l31] = (n == 0 ? accO10[r] : accO11[r]);
        }
    if (hi == 0) {
        Lb2[q0w + l31]      = la;
        Lb2[q0w + 32 + l31] = lb;
    }
#undef STAGE
}

// ================== combine partials -> AO bf16 ==================
// grid (32 qblocks, 64 bn). O = (O1+O2)/(L1+L2), transpose [d][q]->[q][d].
__global__ __launch_bounds__(256) void combineO(
    const float* __restrict__ OpA, const float* __restrict__ OpB,
    const float* __restrict__ LpA, const float* __restrict__ LpB,
    u16* __restrict__ AO)
{
    __shared__ float ot[64][65];
    __shared__ float ls[64];

    const int tid = threadIdx.x;
    const int bn = blockIdx.y;
    const int q0 = blockIdx.x * 64;
    const int b = bn >> 4, head = bn & 15;

    const size_t obase = (size_t)bn * 64 * T_;
    const int qi = tid & 63;
    const int d0 = tid >> 6;

    if (tid < 64)
        ls[tid] = 1.f / (LpA[(size_t)bn * T_ + q0 + tid] + LpB[(size_t)bn * T_ + q0 + tid]);
#pragma unroll
    for (int d = 0; d < 16; ++d) {
        int dd = d0 + d * 4;
        ot[dd][qi] = OpA[obase + (size_t)dd * T_ + q0 + qi]
                   + OpB[obase + (size_t)dd * T_ + q0 + qi];
    }
    __syncthreads();
#pragma unroll
    for (int itq = 0; itq < 2; ++itq) {
        int q = itq * 32 + (tid >> 3);
        int dc = (tid & 7) * 8;
        float inv = ls[q];
        union { u16 h[8]; uint4 v; } o;
#pragma unroll
        for (int j = 0; j < 8; ++j) o.h[j] = f2bf(ot[dc + j][q] * inv);
        *(uint4*)&AO[(size_t)(b * T_ + q0 + q) * (NH_ * DH_) + head * DH_ + dc] = o.v;
    }
}

// ================== fallback single-kernel attention (R6, 82us) ==================
__global__ __launch_bounds__(256, 2) void attn64(
    const u16* __restrict__ Q, const u16* __restrict__ K,
    const u16* __restrict__ Vt, u16* __restrict__ AO)
{
    __shared__ u16 lds[16384];
    char* const base = (char*)lds;

    const int tid = threadIdx.x;
    const int wid = tid >> 6;
    const int lane = tid & 63;
    const int l31 = lane & 31;
    const int hi = lane >> 5;

    const int orig = blockIdx.y * 8 + blockIdx.x;
    const int swz = (orig & 7) * 64 + (orig >> 3);
    const int bn = swz >> 3;
    const int q0w = (swz & 7) * 256 + wid * 64;
    const int b = bn >> 4, head = bn & 15;

    const u16* Qb = Q + ((size_t)bn * T_ + q0w + l31) * DH_;
    const u16* Kb = K + (size_t)bn * T_ * DH_;
    const u16* Vb = Vt + (size_t)bn * DH_ * T_;

    bf16x8 qfa[4], qfb[4];
#pragma unroll
    for (int c = 0; c < 4; ++c) {
        qfa[c] = *(const bf16x8*)(Qb + c * 16 + hi * 8);
        qfb[c] = *(const bf16x8*)(Qb + 32 * DH_ + c * 16 + hi * 8);
    }

    f32x16 accO00, accO01, accO10, accO11;
#pragma unroll
    for (int r = 0; r < 16; ++r) {
        accO00[r] = 0.f; accO01[r] = 0.f;
        accO10[r] = 0.f; accO11[r] = 0.f;
    }
    float la = 0.f, lb = 0.f;

    const int srow = tid >> 3;
    const int scsw = (tid & 7) ^ (srow & 7);
    const int rowsw = l31 & 7;

    const u16* kSrc = Kb + (size_t)srow * DH_ + scsw * 8;
    const u16* vSrc = Vb + (size_t)srow * T_ + scsw * 8;

#define STAGE(dK, dV) do { \
    gload16(kSrc,            (dK) + tid * 16); \
    gload16(kSrc + 32 * DH_, (dK) + 4096 + tid * 16); \
    gload16(vSrc,            (dV) + tid * 16); \
    gload16(vSrc + 32 * T_,  (dV) + 4096 + tid * 16); \
    kSrc += KVB * DH_; vSrc += KVB; } while (0)

    char* const kb0 = base;
    char* const vb0 = base + 8192;
    char* const kb1 = base + 16384;
    char* const vb1 = base + 24576;

    auto process = [&](const char* kc, const char* vc) {
        f32x16 sA0, sA1, sB0, sB1;
#pragma unroll
        for (int r = 0; r < 16; ++r) { sA0[r] = 0.f; sA1[r] = 0.f; sB0[r] = 0.f; sB1[r] = 0.f; }
        __builtin_amdgcn_s_setprio(1);
#pragma unroll
        for (int c = 0; c < 4; ++c) {
            const int c16 = ((2 * c + hi) ^ rowsw) * 16;
            bf16x8 k0 = *(const bf16x8*)(kc + l31 * 128 + c16);
            bf16x8 k1 = *(const bf16x8*)(kc + 4096 + l31 * 128 + c16);
            sA0 = mfma32(k0, qfa[c], sA0);
            sA1 = mfma32(k1, qfa[c], sA1);
            sB0 = mfma32(k0, qfb[c], sB0);
            sB1 = mfma32(k1, qfb[c], sB1);
        }
        __builtin_amdgcn_s_setprio(0);

#pragma unroll
        for (int r = 0; r < 16; ++r) {
            sA0[r] = exp2_fast(sA0[r]);
            sA1[r] = exp2_fast(sA1[r]);
            sB0[r] = exp2_fast(sB0[r]);
            sB1[r] = exp2_fast(sB1[r]);
        }
        float ta = 0.f, tb2 = 0.f;
#pragma unroll
        for (int r = 0; r < 16; ++r) {
            ta  += sA0[r] + sA1[r];
            tb2 += sB0[r] + sB1[r];
        }
        la += ta; lb += tb2;

        unsigned w0a[8], w1a[8], w0b[8], w1b[8];
#pragma unroll
        for (int k2 = 0; k2 < 8; ++k2) {
            w0a[k2] = packbf2(sA0[2 * k2], sA0[2 * k2 + 1]);
            w1a[k2] = packbf2(sA1[2 * k2], sA1[2 * k2 + 1]);
            w0b[k2] = packbf2(sB0[2 * k2], sB0[2 * k2 + 1]);
            w1b[k2] = packbf2(sB1[2 * k2], sB1[2 * k2 + 1]);
        }
        plswap(w0a[0], w0a[2]); plswap(w0a[1], w0a[3]);
        plswap(w0a[4], w0a[6]); plswap(w0a[5], w0a[7]);
        plswap(w1a[0], w1a[2]); plswap(w1a[1], w1a[3]);
        plswap(w1a[4], w1a[6]); plswap(w1a[5], w1a[7]);
        plswap(w0b[0], w0b[2]); plswap(w0b[1], w0b[3]);
        plswap(w0b[4], w0b[6]); plswap(w0b[5], w0b[7]);
        plswap(w1b[0], w1b[2]); plswap(w1b[1], w1b[3]);
        plswap(w1b[4], w1b[6]); plswap(w1b[5], w1b[7]);

        __builtin_amdgcn_s_setprio(1);
#pragma unroll
        for (int ks = 0; ks < 4; ++ks) {
            union { unsigned w[4]; bf16x8 v; } pa, pb;
            const unsigned* sa_ = (ks < 2) ? w0a : w1a;
            const unsigned* sb_ = (ks < 2) ? w0b : w1b;
            const int o = (ks & 1) * 4;
            pa.w[0] = sa_[o + 0]; pa.w[1] = sa_[o + 1];
            pa.w[2] = sa_[o + 2]; pa.w[3] = sa_[o + 3];
            pb.w[0] = sb_[o + 0]; pb.w[1] = sb_[o + 1];
            pb.w[2] = sb_[o + 2]; pb.w[3] = sb_[o + 3];
            const int c16 = ((2 * ks + hi) ^ rowsw) * 16;
            bf16x8 v0f = *(const bf16x8*)(vc + l31 * 128 + c16);
            bf16x8 v1f = *(const bf16x8*)(vc + 4096 + l31 * 128 + c16);
            accO00 = mfma32(v0f, pa.v, accO00);
            accO01 = mfma32(v1f, pa.v, accO01);
            accO10 = mfma32(v0f, pb.v, accO10);
            accO11 = mfma32(v1f, pb.v, accO11);
        }
        __builtin_amdgcn_s_setprio(0);
    };

    STAGE(kb0, vb0);
    __syncthreads();

    for (int it = 0; it < T_ / KVB; it += 2) {
        STAGE(kb1, vb1);
        process(kb0, vb0);
        __syncthreads();
        if (it + 2 < T_ / KVB) STAGE(kb0, vb0);
        process(kb1, vb1);
        __syncthreads();
    }

    la += __shfl_xor(la, 32);
    lb += __shfl_xor(lb, 32);

    char* myO = base + wid * 8192;
    float inva = 1.f / la;
    float invb = 1.f / lb;
#pragma unroll
    for (int n = 0; n < 2; ++n)
#pragma unroll
        for (int r = 0; r < 16; ++r) {
            int d = n * 32 + (r & 3) + 8 * (r >> 2) + 4 * hi;
            int c16 = (d >> 3) ^ rowsw;
            float va = (n == 0 ? accO00[r] : accO01[r]) * inva;
            float vb2 = (n == 0 ? accO10[r] : accO11[r]) * invb;
            *(u16*)(myO + l31 * 128 + c16 * 16 + (d & 7) * 2) = f2bf(va);
            *(u16*)(myO + (32 + l31) * 128 + c16 * 16 + (d & 7) * 2) = f2bf(vb2);
        }
    asm volatile("s_waitcnt lgkmcnt(0)" ::: "memory");
#pragma unroll
    for (int it = 0; it < 8; ++it) {
        int id = lane + it * 64;
        int row = id >> 3;
        int c = id & 7;
        int c16s = c ^ (row & 7);
        uint4 val = *(const uint4*)(myO + row * 128 + c16s * 16);
        *(uint4*)&AO[(size_t)(b * T_ + q0w + row) * (NH_ * DH_) + head * DH_ + c * 8] = val;
    }
#undef STAGE
}

// ---------------- host launch ----------------
extern "C" void kernel_launch(void* const* d_in, const int* in_sizes, int n_in,
                              void* d_out, int out_size, void* d_ws, size_t ws_size,
                              hipStream_t stream)
{
    const float* query = (const float*)d_in[0];
    const float* value = (const float*)d_in[1];
    const float* Wq = (const float*)d_in[2];
    const float* bq = (const float*)d_in[3];
    const float* Wk = (const float*)d_in[4];
    const float* bk = (const float*)d_in[5];
    const float* Wv = (const float*)d_in[6];
    const float* bv = (const float*)d_in[7];
    const float* Wo = (const float*)d_in[8];
    const float* bo = (const float*)d_in[9];
    float* out = (float*)d_out;

    u16* ws = (u16*)d_ws;
    char* wsb = (char*)d_ws;
    const size_t E8M = (size_t)8 << 20;
    const size_t MB = (size_t)1 << 20;
    u16* qbf = ws;                    // [0, 16MB)
    u16* vbf = ws + E8M;              // [16, 32)
    u16* Wqb = ws + 2 * E8M;          // [32, 34)
    u16* Wkb = Wqb + (1u << 20);      // [34, 36)
    u16* Wvb = Wkb + (1u << 20);      // [36, 38)
    u16* Wob = Wvb + (1u << 20);      // [38, 40)
    u16* Qd  = Wob + (1u << 20);      // [40, 56)
    u16* Kd  = Qd + E8M;              // [56, 72)
    u16* Vtd = Kd + E8M;              // [72, 88)
    u16* AO  = Vtd + E8M;             // [88, 104)
    // KV-split partials (reuse dead regions + extend):
    float* OpA = (float*)wsb;                 // [0, 32) - qbf/vbf dead after gemm_qkv
    float* LpA = (float*)(wsb + 32 * MB);     // [32, 32.5) - Wqb dead
    float* LpB = (float*)(wsb + 32 * MB + 512 * 1024);  // [32.5, 33)
    float* OpB = (float*)(wsb + 104 * MB);    // [104, 136) - extension
    const size_t NEED = 136 * MB;

    const int nBig = (B_ * T_ * H_) / 4;
    const int nW   = (KDIM * KDIM) / 4;
    f2bf_hex<<<dim3(512, 6), 256, 0, stream>>>(
        query, qbf, nBig, value, vbf, nBig,
        Wq, Wqb, nW, Wk, Wkb, nW, Wv, Wvb, nW, Wo, Wob, nW);

    gemm_qkv<<<dim3(24, 64), 256, 0, stream>>>(qbf, vbf, Wqb, Wkb, Wvb,
                                               bq, bk, bv, Qd, Kd, Vtd);

    if (ws_size >= NEED) {
        attnP<<<dim3(16, 64), 256, 0, stream>>>(Qd, Kd, Vtd, OpA, OpB, LpA, LpB);
        combineO<<<dim3(32, 64), 256, 0, stream>>>(OpA, OpB, LpA, LpB, AO);
    } else {
        attn64<<<dim3(8, 64), 256, 0, stream>>>(Qd, Kd, Vtd, AO);
    }

    gemm_out<<<dim3(8, 64), 256, 0, stream>>>(AO, Wob, bo, out);
}

// Round 9
// 238.447 us; speedup vs baseline: 3.2779x; 3.2779x over previous
//
#include <hip/hip_runtime.h>
#include <cstdint>
#include <cstddef>

typedef unsigned short u16;
typedef __bf16 bf16x8 __attribute__((ext_vector_type(8)));
typedef __bf16 bf16x2 __attribute__((ext_vector_type(2)));
typedef float f32x4 __attribute__((ext_vector_type(4)));
typedef float f32x16 __attribute__((ext_vector_type(16)));

#define B_   4
#define T_   2048
#define H_   1024
#define NH_  16
#define DH_  64
#define M_   (B_ * T_)      // 8192
#define KDIM 1024
// SCALE * log2(e): scores computed directly in log2 domain
#define QSCALE 0.18033688011112042f

#define BM 128
#define BN 128
#define BK 32

__device__ __forceinline__ u16 f2bf(float f) {
    unsigned u = __float_as_uint(f);
    unsigned r = (u + 0x7fffu + ((u >> 16) & 1u)) >> 16;  // RNE
    return (u16)r;
}

__device__ __forceinline__ unsigned packbf2(float a, float b) {
    bf16x2 v = { (__bf16)a, (__bf16)b };   // compiler emits v_cvt_pk_bf16_f32
    return __builtin_bit_cast(unsigned, v);
}

__device__ __forceinline__ float exp2_fast(float x) {
#if __has_builtin(__builtin_amdgcn_exp2f)
    return __builtin_amdgcn_exp2f(x);
#else
    return exp2f(x);
#endif
}

// in-place half-wave swap
__device__ __forceinline__ void plswap(unsigned &a, unsigned &b) {
#if __has_builtin(__builtin_amdgcn_permlane32_swap)
    auto r = __builtin_amdgcn_permlane32_swap(a, b, false, false);
    a = (unsigned)r[0]; b = (unsigned)r[1];
#else
    int hi = (threadIdx.x & 32);
    unsigned x = (unsigned)__shfl_xor((int)(hi ? b : a), 32);
    unsigned na = hi ? x : a;
    unsigned nb = hi ? b : x;
    a = na; b = nb;
#endif
}

__device__ __forceinline__ void gload16(const void* g, void* l) {
    __builtin_amdgcn_global_load_lds(
        (const __attribute__((address_space(1))) unsigned int*)g,
        (__attribute__((address_space(3))) unsigned int*)l,
        16, 0, 0);
}

__device__ __forceinline__ f32x16 mfma32(bf16x8 a, bf16x8 b, f32x16 c) {
    return __builtin_amdgcn_mfma_f32_32x32x16_bf16(a, b, c, 0, 0, 0);
}

// fused drain + barrier: ds_reads AND staged vmem both complete before cross
__device__ __forceinline__ void wait_barrier() {
    asm volatile("s_waitcnt vmcnt(0) lgkmcnt(0)\n\ts_barrier" ::: "memory");
}

// ---------------- fp32 -> bf16 converts (single launch, 6 jobs) ----------------
__global__ __launch_bounds__(256) void f2bf_hex(
    const float* s0, u16* d0, int n0, const float* s1, u16* d1, int n1,
    const float* s2, u16* d2, int n2, const float* s3, u16* d3, int n3,
    const float* s4, u16* d4, int n4j, const float* s5, u16* d5, int n5)
{
    const float* s; u16* d; int n;
    switch (blockIdx.y) {
        case 0: s = s0; d = d0; n = n0; break;
        case 1: s = s1; d = d1; n = n1; break;
        case 2: s = s2; d = d2; n = n2; break;
        case 3: s = s3; d = d3; n = n3; break;
        case 4: s = s4; d = d4; n = n4j; break;
        default: s = s5; d = d5; n = n5; break;
    }
    int i = blockIdx.x * blockDim.x + threadIdx.x;
    int stride = gridDim.x * blockDim.x;
    for (; i < n; i += stride) {
        float4 f = reinterpret_cast<const float4*>(s)[i];
        ushort4 o;
        o.x = f2bf(f.x); o.y = f2bf(f.y); o.z = f2bf(f.z); o.w = f2bf(f.w);
        reinterpret_cast<ushort4*>(d)[i] = o;
    }
}

// ---------------- 128x128 bf16 GEMM core  C = X * W^T ----------------
// Double-buffered K-loop: stage k+1 early, ONE drain+barrier per K-step.
__device__ __forceinline__ void gemm_core(
    const u16* __restrict__ X, const u16* __restrict__ W,
    const float* __restrict__ bias,
    u16* __restrict__ dst_bf, float* __restrict__ dst_f,
    float scale, int mode, int r0, int c0)
{
    __shared__ u16 lds[17408];
    char* const base = (char*)lds;

    const int tid = threadIdx.x;
    const int wid = tid >> 6;
    const int l15 = tid & 15;
    const int l4  = (tid & 63) >> 4;
    const int wr = wid >> 1, wc = wid & 1;

    const u16* gA = X + (size_t)(r0 + (tid >> 2)) * KDIM + (tid & 3) * 8;
    const u16* gB = W + (size_t)(c0 + (tid >> 2)) * KDIM + (tid & 3) * 8;

    f32x4 acc[4][4];
#pragma unroll
    for (int m = 0; m < 4; ++m)
#pragma unroll
        for (int n = 0; n < 4; ++n) acc[m][n] = (f32x4){0.f, 0.f, 0.f, 0.f};

    const int arow = wr * 64 + l15;
    const int brow = wc * 64 + l15;

#define STAGEG(p, kt) do { \
    const u16* pa_ = gA + (kt) * BK; \
    const u16* pb_ = gB + (kt) * BK; \
    char* dA_ = base + (p) * 16384 + wid * 1024; \
    char* dB_ = dA_ + 8192; \
    gload16(pa_, dA_); gload16(pa_ + 64 * KDIM, dA_ + 4096); \
    gload16(pb_, dB_); gload16(pb_ + 64 * KDIM, dB_ + 4096); } while (0)

    STAGEG(0, 0);
    wait_barrier();

    for (int kt = 0; kt < KDIM / BK; ++kt) {
        if (kt + 1 < KDIM / BK) STAGEG((kt + 1) & 1, kt + 1);
        const char* bufp = base + (kt & 1) * 16384;
        bf16x8 a[4], b[4];
#pragma unroll
        for (int m = 0; m < 4; ++m)
            a[m] = *(const bf16x8*)(bufp + (arow + m * 16) * 64 + l4 * 16);
#pragma unroll
        for (int n = 0; n < 4; ++n)
            b[n] = *(const bf16x8*)(bufp + 8192 + (brow + n * 16) * 64 + l4 * 16);
#pragma unroll
        for (int m = 0; m < 4; ++m)
#pragma unroll
            for (int n = 0; n < 4; ++n)
                acc[m][n] = __builtin_amdgcn_mfma_f32_16x16x32_bf16(a[m], b[n], acc[m][n], 0, 0, 0);
        wait_barrier();
    }
#undef STAGEG

    if (mode == 2) {
#pragma unroll
        for (int m = 0; m < 4; ++m)
#pragma unroll
            for (int n = 0; n < 4; ++n) {
                int cg = c0 + wc * 64 + n * 16 + l15;
                float bv = bias[cg];
                int rg = r0 + wr * 64 + m * 16 + l4 * 4;
#pragma unroll
                for (int j = 0; j < 4; ++j)
                    dst_f[(size_t)(rg + j) * H_ + cg] = acc[m][n][j] + bv;
            }
    } else if (mode == 0) {
        __syncthreads();
        u16 (*ldsR)[136] = (u16(*)[136])lds;
#pragma unroll
        for (int m = 0; m < 4; ++m)
#pragma unroll
            for (int n = 0; n < 4; ++n) {
                int cl = wc * 64 + n * 16 + l15;
                float bv = bias[c0 + cl];
                int rl = wr * 64 + m * 16 + l4 * 4;
#pragma unroll
                for (int j = 0; j < 4; ++j)
                    ldsR[rl + j][cl] = f2bf((acc[m][n][j] + bv) * scale);
            }
        __syncthreads();
        int b2 = r0 >> 11, tb = r0 & (T_ - 1);
#pragma unroll
        for (int it = 0; it < 8; ++it) {
            int id = tid + it * 256;
            int row = id >> 4;
            int ch = id & 15;
            int head = (c0 >> 6) + (ch >> 3);
            int d0 = (ch & 7) * 8;
            uint4 v = *(const uint4*)&ldsR[row][ch * 8];
            *(uint4*)&dst_bf[(((size_t)(b2 * NH_ + head) * T_ + tb + row) << 6) + d0] = v;
        }
    } else {
        __syncthreads();
        u16 (*ldsT)[136] = (u16(*)[136])lds;
#pragma unroll
        for (int m = 0; m < 4; ++m)
#pragma unroll
            for (int n = 0; n < 4; ++n) {
                int cl = wc * 64 + n * 16 + l15;
                float bv = bias[c0 + cl];
                int rl = wr * 64 + m * 16 + l4 * 4;
#pragma unroll
                for (int j = 0; j < 4; ++j)
                    ldsT[cl][rl + j] = f2bf(acc[m][n][j] + bv);
            }
        __syncthreads();
        int b = r0 >> 11, tb = r0 & (T_ - 1);
#pragma unroll
        for (int it = 0; it < 8; ++it) {
            int chunk = tid + it * 256;
            int cl = chunk >> 4;
            int r8 = (chunk & 15) << 3;
            int cg = c0 + cl;
            int head = cg >> 6, d = cg & 63;
            uint4 v = *(const uint4*)&ldsT[cl][r8];
            *(uint4*)&dst_bf[((size_t)((b * NH_ + head) * DH_ + d) * T_) + tb + r8] = v;
        }
    }
}

// Fused QKV projection: grid (24,64). bx 0-7: Q, 8-15: K, 16-23: V.
__global__ __launch_bounds__(256) void gemm_qkv(
    const u16* __restrict__ qbf, const u16* __restrict__ vbf,
    const u16* __restrict__ Wqb, const u16* __restrict__ Wkb, const u16* __restrict__ Wvb,
    const float* __restrict__ bq, const float* __restrict__ bk, const float* __restrict__ bv,
    u16* __restrict__ Qd, u16* __restrict__ Kd, u16* __restrict__ Vtd)
{
    const int orig = blockIdx.y * 24 + blockIdx.x;
    const int swz = (orig & 7) * 192 + (orig >> 3);
    const int bx = swz % 24;
    const int by = swz / 24;
    const int seg = bx >> 3;
    const int r0 = by * BM;
    const int c0 = (bx & 7) * BN;

    if (seg == 0)
        gemm_core(qbf, Wqb, bq, Qd, nullptr, QSCALE, 0, r0, c0);
    else if (seg == 1)
        gemm_core(vbf, Wkb, bk, Kd, nullptr, 1.0f, 0, r0, c0);
    else
        gemm_core(vbf, Wvb, bv, Vtd, nullptr, 1.0f, 1, r0, c0);
}

// Output projection: grid (8,64). XCD swizzle chunk=64.
__global__ __launch_bounds__(256) void gemm_out(
    const u16* __restrict__ AO, const u16* __restrict__ Wob,
    const float* __restrict__ bo, float* __restrict__ out)
{
    const int orig = blockIdx.y * 8 + blockIdx.x;
    const int swz = (orig & 7) * 64 + (orig >> 3);
    const int bx = swz & 7;
    const int by = swz >> 3;
    gemm_core(AO, Wob, bo, nullptr, out, 1.0f, 2, by * BM, bx * BN);
}

#define KVB 64

// ================== KV-split partial attention ==================
// Each block: 256 q rows x HALF the kv range. Grid (16,64) = 1024 blocks =
// 4 blocks/CU (validated by R7's 33% occupancy even while spilling).
// NO min-waves launch bound: R7's (256,4) capped unified regs at 128 and
// spilled everything (VGPR 64, 1.4GB scratch WRITE). Default bound lets the
// compiler take ~190 unified regs; pool 2048/SIMD still fits 4 waves/SIMD.
__global__ __launch_bounds__(256) void attnP(
    const u16* __restrict__ Q, const u16* __restrict__ K,
    const u16* __restrict__ Vt,
    float* __restrict__ OpA, float* __restrict__ OpB,
    float* __restrict__ LpA, float* __restrict__ LpB)
{
    __shared__ u16 lds[16384];   // 32KB: K0|V0|K1|V1, 8KB each
    char* const base = (char*)lds;

    const int tid = threadIdx.x;
    const int wid = tid >> 6;
    const int lane = tid & 63;
    const int l31 = lane & 31;
    const int hi = lane >> 5;

    // XCD swizzle: nwg=1024, chunk=128 => 8 whole heads per XCD
    const int orig = blockIdx.y * 16 + blockIdx.x;
    const int swz = (orig & 7) * 128 + (orig >> 3);
    const int bn = swz >> 4;
    const int rest = swz & 15;
    const int h = rest >> 3;                       // kv half
    const int q0w = (rest & 7) * 256 + wid * 64;   // wave's q base
    const int kv0 = h * (T_ / 2);

    const u16* Qb = Q + ((size_t)bn * T_ + q0w + l31) * DH_;
    const u16* Kb = K + (size_t)bn * T_ * DH_;
    const u16* Vb = Vt + (size_t)bn * DH_ * T_;

    bf16x8 qfa[4], qfb[4];
#pragma unroll
    for (int c = 0; c < 4; ++c) {
        qfa[c] = *(const bf16x8*)(Qb + c * 16 + hi * 8);
        qfb[c] = *(const bf16x8*)(Qb + 32 * DH_ + c * 16 + hi * 8);
    }

    f32x16 accO00, accO01, accO10, accO11;
#pragma unroll
    for (int r = 0; r < 16; ++r) {
        accO00[r] = 0.f; accO01[r] = 0.f;
        accO10[r] = 0.f; accO11[r] = 0.f;
    }
    float la = 0.f, lb = 0.f;

    const int srow = tid >> 3;
    const int scsw = (tid & 7) ^ (srow & 7);
    const int rowsw = l31 & 7;

    const u16* kSrc = Kb + (size_t)(kv0 + srow) * DH_ + scsw * 8;
    const u16* vSrc = Vb + (size_t)srow * T_ + kv0 + scsw * 8;

#define STAGE(dK, dV) do { \
    gload16(kSrc,            (dK) + tid * 16); \
    gload16(kSrc + 32 * DH_, (dK) + 4096 + tid * 16); \
    gload16(vSrc,            (dV) + tid * 16); \
    gload16(vSrc + 32 * T_,  (dV) + 4096 + tid * 16); \
    kSrc += KVB * DH_; vSrc += KVB; } while (0)

    char* const kb0 = base;
    char* const vb0 = base + 8192;
    char* const kb1 = base + 16384;
    char* const vb1 = base + 24576;

    auto process = [&](const char* kc, const char* vc) {
        f32x16 sA0, sA1, sB0, sB1;
#pragma unroll
        for (int r = 0; r < 16; ++r) { sA0[r] = 0.f; sA1[r] = 0.f; sB0[r] = 0.f; sB1[r] = 0.f; }
        __builtin_amdgcn_s_setprio(1);
#pragma unroll
        for (int c = 0; c < 4; ++c) {
            const int c16 = ((2 * c + hi) ^ rowsw) * 16;
            bf16x8 k0 = *(const bf16x8*)(kc + l31 * 128 + c16);
            bf16x8 k1 = *(const bf16x8*)(kc + 4096 + l31 * 128 + c16);
            sA0 = mfma32(k0, qfa[c], sA0);
            sA1 = mfma32(k1, qfa[c], sA1);
            sB0 = mfma32(k0, qfb[c], sB0);
            sB1 = mfma32(k1, qfb[c], sB1);
        }
        __builtin_amdgcn_s_setprio(0);

#pragma unroll
        for (int r = 0; r < 16; ++r) {
            sA0[r] = exp2_fast(sA0[r]);
            sA1[r] = exp2_fast(sA1[r]);
            sB0[r] = exp2_fast(sB0[r]);
            sB1[r] = exp2_fast(sB1[r]);
        }
        float ta = 0.f, tb2 = 0.f;
#pragma unroll
        for (int r = 0; r < 16; ++r) {
            ta  += sA0[r] + sA1[r];
            tb2 += sB0[r] + sB1[r];
        }
        la += ta; lb += tb2;

        unsigned w0a[8], w1a[8], w0b[8], w1b[8];
#pragma unroll
        for (int k2 = 0; k2 < 8; ++k2) {
            w0a[k2] = packbf2(sA0[2 * k2], sA0[2 * k2 + 1]);
            w1a[k2] = packbf2(sA1[2 * k2], sA1[2 * k2 + 1]);
            w0b[k2] = packbf2(sB0[2 * k2], sB0[2 * k2 + 1]);
            w1b[k2] = packbf2(sB1[2 * k2], sB1[2 * k2 + 1]);
        }
        plswap(w0a[0], w0a[2]); plswap(w0a[1], w0a[3]);
        plswap(w0a[4], w0a[6]); plswap(w0a[5], w0a[7]);
        plswap(w1a[0], w1a[2]); plswap(w1a[1], w1a[3]);
        plswap(w1a[4], w1a[6]); plswap(w1a[5], w1a[7]);
        plswap(w0b[0], w0b[2]); plswap(w0b[1], w0b[3]);
        plswap(w0b[4], w0b[6]); plswap(w0b[5], w0b[7]);
        plswap(w1b[0], w1b[2]); plswap(w1b[1], w1b[3]);
        plswap(w1b[4], w1b[6]); plswap(w1b[5], w1b[7]);

        __builtin_amdgcn_s_setprio(1);
#pragma unroll
        for (int ks = 0; ks < 4; ++ks) {
            union { unsigned w[4]; bf16x8 v; } pa, pb;
            const unsigned* sa_ = (ks < 2) ? w0a : w1a;
            const unsigned* sb_ = (ks < 2) ? w0b : w1b;
            const int o = (ks & 1) * 4;
            pa.w[0] = sa_[o + 0]; pa.w[1] = sa_[o + 1];
            pa.w[2] = sa_[o + 2]; pa.w[3] = sa_[o + 3];
            pb.w[0] = sb_[o + 0]; pb.w[1] = sb_[o + 1];
            pb.w[2] = sb_[o + 2]; pb.w[3] = sb_[o + 3];
            const int c16 = ((2 * ks + hi) ^ rowsw) * 16;
            bf16x8 v0f = *(const bf16x8*)(vc + l31 * 128 + c16);
            bf16x8 v1f = *(const bf16x8*)(vc + 4096 + l31 * 128 + c16);
            accO00 = mfma32(v0f, pa.v, accO00);
            accO01 = mfma32(v1f, pa.v, accO01);
            accO10 = mfma32(v0f, pb.v, accO10);
            accO11 = mfma32(v1f, pb.v, accO11);
        }
        __builtin_amdgcn_s_setprio(0);
    };

    STAGE(kb0, vb0);
    __syncthreads();

    const int NT = (T_ / 2) / KVB;   // 16
    for (int it = 0; it < NT; it += 2) {
        STAGE(kb1, vb1);
        process(kb0, vb0);
        __syncthreads();
        if (it + 2 < NT) STAGE(kb0, vb0);
        process(kb1, vb1);
        __syncthreads();
    }

    // ---- epilogue: store unnormalized partials, f32, q-contiguous ----
    la += __shfl_xor(la, 32);
    lb += __shfl_xor(lb, 32);

    float* Ob = (h ? OpB : OpA) + (size_t)bn * 64 * T_;
    float* Lb2 = (h ? LpB : LpA) + (size_t)bn * T_;
#pragma unroll
    for (int n = 0; n < 2; ++n)
#pragma unroll
        for (int r = 0; r < 16; ++r) {
            int d = n * 32 + (r & 3) + 8 * (r >> 2) + 4 * hi;
            Ob[(size_t)d * T_ + q0w + l31]      = (n == 0 ? accO00[r] : accO01[r]);
            Ob[(size_t)d * T_ + q0w + 32 + l31] = (n == 0 ? accO10[r] : accO11[r]);
        }
    if (hi == 0) {
        Lb2[q0w + l31]      = la;
        Lb2[q0w + 32 + l31] = lb;
    }
#undef STAGE
}

// ================== combine partials -> AO bf16 ==================
// grid (32 qblocks, 64 bn). O = (O1+O2)/(L1+L2), transpose [d][q]->[q][d].
__global__ __launch_bounds__(256) void combineO(
    const float* __restrict__ OpA, const float* __restrict__ OpB,
    const float* __restrict__ LpA, const float* __restrict__ LpB,
    u16* __restrict__ AO)
{
    __shared__ float ot[64][65];
    __shared__ float ls[64];

    const int tid = threadIdx.x;
    const int bn = blockIdx.y;
    const int q0 = blockIdx.x * 64;
    const int b = bn >> 4, head = bn & 15;

    const size_t obase = (size_t)bn * 64 * T_;
    const int qi = tid & 63;
    const int d0 = tid >> 6;

    if (tid < 64)
        ls[tid] = 1.f / (LpA[(size_t)bn * T_ + q0 + tid] + LpB[(size_t)bn * T_ + q0 + tid]);
#pragma unroll
    for (int d = 0; d < 16; ++d) {
        int dd = d0 + d * 4;
        ot[dd][qi] = OpA[obase + (size_t)dd * T_ + q0 + qi]
                   + OpB[obase + (size_t)dd * T_ + q0 + qi];
    }
    __syncthreads();
#pragma unroll
    for (int itq = 0; itq < 2; ++itq) {
        int q = itq * 32 + (tid >> 3);
        int dc = (tid & 7) * 8;
        float inv = ls[q];
        union { u16 h[8]; uint4 v; } o;
#pragma unroll
        for (int j = 0; j < 8; ++j) o.h[j] = f2bf(ot[dc + j][q] * inv);
        *(uint4*)&AO[(size_t)(b * T_ + q0 + q) * (NH_ * DH_) + head * DH_ + dc] = o.v;
    }
}

// ================== fallback single-kernel attention (R6, 82us) ==================
__global__ __launch_bounds__(256, 2) void attn64(
    const u16* __restrict__ Q, const u16* __restrict__ K,
    const u16* __restrict__ Vt, u16* __restrict__ AO)
{
    __shared__ u16 lds[16384];
    char* const base = (char*)lds;

    const int tid = threadIdx.x;
    const int wid = tid >> 6;
    const int lane = tid & 63;
    const int l31 = lane & 31;
    const int hi = lane >> 5;

    const int orig = blockIdx.y * 8 + blockIdx.x;
    const int swz = (orig & 7) * 64 + (orig >> 3);
    const int bn = swz >> 3;
    const int q0w = (swz & 7) * 256 + wid * 64;
    const int b = bn >> 4, head = bn & 15;

    const u16* Qb = Q + ((size_t)bn * T_ + q0w + l31) * DH_;
    const u16* Kb = K + (size_t)bn * T_ * DH_;
    const u16* Vb = Vt + (size_t)bn * DH_ * T_;

    bf16x8 qfa[4], qfb[4];
#pragma unroll
    for (int c = 0; c < 4; ++c) {
        qfa[c] = *(const bf16x8*)(Qb + c * 16 + hi * 8);
        qfb[c] = *(const bf16x8*)(Qb + 32 * DH_ + c * 16 + hi * 8);
    }

    f32x16 accO00, accO01, accO10, accO11;
#pragma unroll
    for (int r = 0; r < 16; ++r) {
        accO00[r] = 0.f; accO01[r] = 0.f;
        accO10[r] = 0.f; accO11[r] = 0.f;
    }
    float la = 0.f, lb = 0.f;

    const int srow = tid >> 3;
    const int scsw = (tid & 7) ^ (srow & 7);
    const int rowsw = l31 & 7;

    const u16* kSrc = Kb + (size_t)srow * DH_ + scsw * 8;
    const u16* vSrc = Vb + (size_t)srow * T_ + scsw * 8;

#define STAGE(dK, dV) do { \
    gload16(kSrc,            (dK) + tid * 16); \
    gload16(kSrc + 32 * DH_, (dK) + 4096 + tid * 16); \
    gload16(vSrc,            (dV) + tid * 16); \
    gload16(vSrc + 32 * T_,  (dV) + 4096 + tid * 16); \
    kSrc += KVB * DH_; vSrc += KVB; } while (0)

    char* const kb0 = base;
    char* const vb0 = base + 8192;
    char* const kb1 = base + 16384;
    char* const vb1 = base + 24576;

    auto process = [&](const char* kc, const char* vc) {
        f32x16 sA0, sA1, sB0, sB1;
#pragma unroll
        for (int r = 0; r < 16; ++r) { sA0[r] = 0.f; sA1[r] = 0.f; sB0[r] = 0.f; sB1[r] = 0.f; }
        __builtin_amdgcn_s_setprio(1);
#pragma unroll
        for (int c = 0; c < 4; ++c) {
            const int c16 = ((2 * c + hi) ^ rowsw) * 16;
            bf16x8 k0 = *(const bf16x8*)(kc + l31 * 128 + c16);
            bf16x8 k1 = *(const bf16x8*)(kc + 4096 + l31 * 128 + c16);
            sA0 = mfma32(k0, qfa[c], sA0);
            sA1 = mfma32(k1, qfa[c], sA1);
            sB0 = mfma32(k0, qfb[c], sB0);
            sB1 = mfma32(k1, qfb[c], sB1);
        }
        __builtin_amdgcn_s_setprio(0);

#pragma unroll
        for (int r = 0; r < 16; ++r) {
            sA0[r] = exp2_fast(sA0[r]);
            sA1[r] = exp2_fast(sA1[r]);
            sB0[r] = exp2_fast(sB0[r]);
            sB1[r] = exp2_fast(sB1[r]);
        }
        float ta = 0.f, tb2 = 0.f;
#pragma unroll
        for (int r = 0; r < 16; ++r) {
            ta  += sA0[r] + sA1[r];
            tb2 += sB0[r] + sB1[r];
        }
        la += ta; lb += tb2;

        unsigned w0a[8], w1a[8], w0b[8], w1b[8];
#pragma unroll
        for (int k2 = 0; k2 < 8; ++k2) {
            w0a[k2] = packbf2(sA0[2 * k2], sA0[2 * k2 + 1]);
            w1a[k2] = packbf2(sA1[2 * k2], sA1[2 * k2 + 1]);
            w0b[k2] = packbf2(sB0[2 * k2], sB0[2 * k2 + 1]);
            w1b[k2] = packbf2(sB1[2 * k2], sB1[2 * k2 + 1]);
        }
        plswap(w0a[0], w0a[2]); plswap(w0a[1], w0a[3]);
        plswap(w0a[4], w0a[6]); plswap(w0a[5], w0a[7]);
        plswap(w1a[0], w1a[2]); plswap(w1a[1], w1a[3]);
        plswap(w1a[4], w1a[6]); plswap(w1a[5], w1a[7]);
        plswap(w0b[0], w0b[2]); plswap(w0b[1], w0b[3]);
        plswap(w0b[4], w0b[6]); plswap(w0b[5], w0b[7]);
        plswap(w1b[0], w1b[2]); plswap(w1b[1], w1b[3]);
        plswap(w1b[4], w1b[6]); plswap(w1b[5], w1b[7]);

        __builtin_amdgcn_s_setprio(1);
#pragma unroll
        for (int ks = 0; ks < 4; ++ks) {
            union { unsigned w[4]; bf16x8 v; } pa, pb;
            const unsigned* sa_ = (ks < 2) ? w0a : w1a;
            const unsigned* sb_ = (ks < 2) ? w0b : w1b;
            const int o = (ks & 1) * 4;
            pa.w[0] = sa_[o + 0]; pa.w[1] = sa_[o + 1];
            pa.w[2] = sa_[o + 2]; pa.w[3] = sa_[o + 3];
            pb.w[0] = sb_[o + 0]; pb.w[1] = sb_[o + 1];
            pb.w[2] = sb_[o + 2]; pb.w[3] = sb_[o + 3];
            const int c16 = ((2 * ks + hi) ^ rowsw) * 16;
            bf16x8 v0f = *(const bf16x8*)(vc + l31 * 128 + c16);
            bf16x8 v1f = *(const bf16x8*)(vc + 4096 + l31 * 128 + c16);
            accO00 = mfma32(v0f, pa.v, accO00);
            accO01 = mfma32(v1f, pa.v, accO01);
            accO10 = mfma32(v0f, pb.v, accO10);
            accO11 = mfma32(v1f, pb.v, accO11);
        }
        __builtin_amdgcn_s_setprio(0);
    };

    STAGE(kb0, vb0);
    __syncthreads();

    for (int it = 0; it < T_ / KVB; it += 2) {
        STAGE(kb1, vb1);
        process(kb0, vb0);
        __syncthreads();
        if (it + 2 < T_ / KVB) STAGE(kb0, vb0);
        process(kb1, vb1);
        __syncthreads();
    }

    la += __shfl_xor(la, 32);
    lb += __shfl_xor(lb, 32);

    char* myO = base + wid * 8192;
    float inva = 1.f / la;
    float invb = 1.f / lb;
#pragma unroll
    for (int n = 0; n < 2; ++n)
#pragma unroll
        for (int r = 0; r < 16; ++r) {
            int d = n * 32 + (r & 3) + 8 * (r >> 2) + 4 * hi;
            int c16 = (d >> 3) ^ rowsw;
            float va = (n == 0 ? accO00[r] : accO01[r]) * inva;
            float vb2 = (n == 0 ? accO10[r] : accO11[r]) * invb;
            *(u16*)(myO + l31 * 128 + c16 * 16 + (d & 7) * 2) = f2bf(va);
            *(u16*)(myO + (32 + l31) * 128 + c16 * 16 + (d & 7) * 2) = f2bf(vb2);
        }
    asm volatile("s_waitcnt lgkmcnt(0)" ::: "memory");
#pragma unroll
    for (int it = 0; it < 8; ++it) {
        int id = lane + it * 64;
        int row = id >> 3;
        int c = id & 7;
        int c16s = c ^ (row & 7);
        uint4 val = *(const uint4*)(myO + row * 128 + c16s * 16);
        *(uint4*)&AO[(size_t)(b * T_ + q0w + row) * (NH_ * DH_) + head * DH_ + c * 8] = val;
    }
#undef STAGE
}

// ---------------- host launch ----------------
extern "C" void kernel_launch(void* const* d_in, const int* in_sizes, int n_in,
                              void* d_out, int out_size, void* d_ws, size_t ws_size,
                              hipStream_t stream)
{
    const float* query = (const float*)d_in[0];
    const float* value = (const float*)d_in[1];
    const float* Wq = (const float*)d_in[2];
    const float* bq = (const float*)d_in[3];
    const float* Wk = (const float*)d_in[4];
    const float* bk = (const float*)d_in[5];
    const float* Wv = (const float*)d_in[6];
    const float* bv = (const float*)d_in[7];
    const float* Wo = (const float*)d_in[8];
    const float* bo = (const float*)d_in[9];
    float* out = (float*)d_out;

    u16* ws = (u16*)d_ws;
    char* wsb = (char*)d_ws;
    const size_t E8M = (size_t)8 << 20;
    const size_t MB = (size_t)1 << 20;
    u16* qbf = ws;                    // [0, 16MB)
    u16* vbf = ws + E8M;              // [16, 32)
    u16* Wqb = ws + 2 * E8M;          // [32, 34)
    u16* Wkb = Wqb + (1u << 20);      // [34, 36)
    u16* Wvb = Wkb + (1u << 20);      // [36, 38)
    u16* Wob = Wvb + (1u << 20);      // [38, 40)
    u16* Qd  = Wob + (1u << 20);      // [40, 56)
    u16* Kd  = Qd + E8M;              // [56, 72)
    u16* Vtd = Kd + E8M;              // [72, 88)
    u16* AO  = Vtd + E8M;             // [88, 104)
    // KV-split partials (reuse dead regions + extend):
    float* OpA = (float*)wsb;                 // [0, 32) - qbf/vbf dead after gemm_qkv
    float* LpA = (float*)(wsb + 32 * MB);     // [32, 32.5) - Wqb dead
    float* LpB = (float*)(wsb + 32 * MB + 512 * 1024);  // [32.5, 33)
    float* OpB = (float*)(wsb + 104 * MB);    // [104, 136) - extension
    const size_t NEED = 136 * MB;

    const int nBig = (B_ * T_ * H_) / 4;
    const int nW   = (KDIM * KDIM) / 4;
    f2bf_hex<<<dim3(512, 6), 256, 0, stream>>>(
        query, qbf, nBig, value, vbf, nBig,
        Wq, Wqb, nW, Wk, Wkb, nW, Wv, Wvb, nW, Wo, Wob, nW);

    gemm_qkv<<<dim3(24, 64), 256, 0, stream>>>(qbf, vbf, Wqb, Wkb, Wvb,
                                               bq, bk, bv, Qd, Kd, Vtd);

    if (ws_size >= NEED) {
        attnP<<<dim3(16, 64), 256, 0, stream>>>(Qd, Kd, Vtd, OpA, OpB, LpA, LpB);
        combineO<<<dim3(32, 64), 256, 0, stream>>>(OpA, OpB, LpA, LpB, AO);
    } else {
        attn64<<<dim3(8, 64), 256, 0, stream>>>(Qd, Kd, Vtd, AO);
    }

    gemm_out<<<dim3(8, 64), 256, 0, stream>>>(AO, Wob, bo, out);
}

// Round 10
// 208.436 us; speedup vs baseline: 3.7499x; 1.1440x over previous
//
#include <hip/hip_runtime.h>
#include <cstdint>
#include <cstddef>

typedef unsigned short u16;
typedef __bf16 bf16x8 __attribute__((ext_vector_type(8)));
typedef __bf16 bf16x2 __attribute__((ext_vector_type(2)));
typedef float f32x4 __attribute__((ext_vector_type(4)));
typedef float f32x16 __attribute__((ext_vector_type(16)));

#define B_   4
#define T_   2048
#define H_   1024
#define NH_  16
#define DH_  64
#define M_   (B_ * T_)      // 8192
#define KDIM 1024
// SCALE * log2(e): scores computed directly in log2 domain
#define QSCALE 0.18033688011112042f

#define BM 128
#define BN 128
#define BK 32

__device__ __forceinline__ u16 f2bf(float f) {
    unsigned u = __float_as_uint(f);
    unsigned r = (u + 0x7fffu + ((u >> 16) & 1u)) >> 16;  // RNE
    return (u16)r;
}

__device__ __forceinline__ unsigned packbf2(float a, float b) {
    bf16x2 v = { (__bf16)a, (__bf16)b };   // compiler emits v_cvt_pk_bf16_f32
    return __builtin_bit_cast(unsigned, v);
}

__device__ __forceinline__ float exp2_fast(float x) {
#if __has_builtin(__builtin_amdgcn_exp2f)
    return __builtin_amdgcn_exp2f(x);
#else
    return exp2f(x);
#endif
}

// in-place half-wave swap
__device__ __forceinline__ void plswap(unsigned &a, unsigned &b) {
#if __has_builtin(__builtin_amdgcn_permlane32_swap)
    auto r = __builtin_amdgcn_permlane32_swap(a, b, false, false);
    a = (unsigned)r[0]; b = (unsigned)r[1];
#else
    int hi = (threadIdx.x & 32);
    unsigned x = (unsigned)__shfl_xor((int)(hi ? b : a), 32);
    unsigned na = hi ? x : a;
    unsigned nb = hi ? b : x;
    a = na; b = nb;
#endif
}

__device__ __forceinline__ void gload16(const void* g, void* l) {
    __builtin_amdgcn_global_load_lds(
        (const __attribute__((address_space(1))) unsigned int*)g,
        (__attribute__((address_space(3))) unsigned int*)l,
        16, 0, 0);
}

__device__ __forceinline__ f32x16 mfma32(bf16x8 a, bf16x8 b, f32x16 c) {
    return __builtin_amdgcn_mfma_f32_32x32x16_bf16(a, b, c, 0, 0, 0);
}

// fused drain + barrier: ds_reads AND staged vmem both complete before cross
__device__ __forceinline__ void wait_barrier() {
    asm volatile("s_waitcnt vmcnt(0) lgkmcnt(0)\n\ts_barrier" ::: "memory");
}

// ---------------- fp32 -> bf16 converts (single launch, 6 jobs) ----------------
__global__ __launch_bounds__(256) void f2bf_hex(
    const float* s0, u16* d0, int n0, const float* s1, u16* d1, int n1,
    const float* s2, u16* d2, int n2, const float* s3, u16* d3, int n3,
    const float* s4, u16* d4, int n4j, const float* s5, u16* d5, int n5)
{
    const float* s; u16* d; int n;
    switch (blockIdx.y) {
        case 0: s = s0; d = d0; n = n0; break;
        case 1: s = s1; d = d1; n = n1; break;
        case 2: s = s2; d = d2; n = n2; break;
        case 3: s = s3; d = d3; n = n3; break;
        case 4: s = s4; d = d4; n = n4j; break;
        default: s = s5; d = d5; n = n5; break;
    }
    int i = blockIdx.x * blockDim.x + threadIdx.x;
    int stride = gridDim.x * blockDim.x;
    for (; i < n; i += stride) {
        float4 f = reinterpret_cast<const float4*>(s)[i];
        ushort4 o;
        o.x = f2bf(f.x); o.y = f2bf(f.y); o.z = f2bf(f.z); o.w = f2bf(f.w);
        reinterpret_cast<ushort4*>(d)[i] = o;
    }
}

// ---------------- 128x128 bf16 GEMM core  C = X * W^T ----------------
// Double-buffered K-loop: stage k+1 early, ONE drain+barrier per K-step.
__device__ __forceinline__ void gemm_core(
    const u16* __restrict__ X, const u16* __restrict__ W,
    const float* __restrict__ bias,
    u16* __restrict__ dst_bf, float* __restrict__ dst_f,
    float scale, int mode, int r0, int c0)
{
    __shared__ u16 lds[17408];
    char* const base = (char*)lds;

    const int tid = threadIdx.x;
    const int wid = tid >> 6;
    const int l15 = tid & 15;
    const int l4  = (tid & 63) >> 4;
    const int wr = wid >> 1, wc = wid & 1;

    const u16* gA = X + (size_t)(r0 + (tid >> 2)) * KDIM + (tid & 3) * 8;
    const u16* gB = W + (size_t)(c0 + (tid >> 2)) * KDIM + (tid & 3) * 8;

    f32x4 acc[4][4];
#pragma unroll
    for (int m = 0; m < 4; ++m)
#pragma unroll
        for (int n = 0; n < 4; ++n) acc[m][n] = (f32x4){0.f, 0.f, 0.f, 0.f};

    const int arow = wr * 64 + l15;
    const int brow = wc * 64 + l15;

#define STAGEG(p, kt) do { \
    const u16* pa_ = gA + (kt) * BK; \
    const u16* pb_ = gB + (kt) * BK; \
    char* dA_ = base + (p) * 16384 + wid * 1024; \
    char* dB_ = dA_ + 8192; \
    gload16(pa_, dA_); gload16(pa_ + 64 * KDIM, dA_ + 4096); \
    gload16(pb_, dB_); gload16(pb_ + 64 * KDIM, dB_ + 4096); } while (0)

    STAGEG(0, 0);
    wait_barrier();

    for (int kt = 0; kt < KDIM / BK; ++kt) {
        if (kt + 1 < KDIM / BK) STAGEG((kt + 1) & 1, kt + 1);
        const char* bufp = base + (kt & 1) * 16384;
        bf16x8 a[4], b[4];
#pragma unroll
        for (int m = 0; m < 4; ++m)
            a[m] = *(const bf16x8*)(bufp + (arow + m * 16) * 64 + l4 * 16);
#pragma unroll
        for (int n = 0; n < 4; ++n)
            b[n] = *(const bf16x8*)(bufp + 8192 + (brow + n * 16) * 64 + l4 * 16);
#pragma unroll
        for (int m = 0; m < 4; ++m)
#pragma unroll
            for (int n = 0; n < 4; ++n)
                acc[m][n] = __builtin_amdgcn_mfma_f32_16x16x32_bf16(a[m], b[n], acc[m][n], 0, 0, 0);
        wait_barrier();
    }
#undef STAGEG

    if (mode == 2) {
#pragma unroll
        for (int m = 0; m < 4; ++m)
#pragma unroll
            for (int n = 0; n < 4; ++n) {
                int cg = c0 + wc * 64 + n * 16 + l15;
                float bv = bias[cg];
                int rg = r0 + wr * 64 + m * 16 + l4 * 4;
#pragma unroll
                for (int j = 0; j < 4; ++j)
                    dst_f[(size_t)(rg + j) * H_ + cg] = acc[m][n][j] + bv;
            }
    } else if (mode == 0) {
        __syncthreads();
        u16 (*ldsR)[136] = (u16(*)[136])lds;
#pragma unroll
        for (int m = 0; m < 4; ++m)
#pragma unroll
            for (int n = 0; n < 4; ++n) {
                int cl = wc * 64 + n * 16 + l15;
                float bv = bias[c0 + cl];
                int rl = wr * 64 + m * 16 + l4 * 4;
#pragma unroll
                for (int j = 0; j < 4; ++j)
                    ldsR[rl + j][cl] = f2bf((acc[m][n][j] + bv) * scale);
            }
        __syncthreads();
        int b2 = r0 >> 11, tb = r0 & (T_ - 1);
#pragma unroll
        for (int it = 0; it < 8; ++it) {
            int id = tid + it * 256;
            int row = id >> 4;
            int ch = id & 15;
            int head = (c0 >> 6) + (ch >> 3);
            int d0 = (ch & 7) * 8;
            uint4 v = *(const uint4*)&ldsR[row][ch * 8];
            *(uint4*)&dst_bf[(((size_t)(b2 * NH_ + head) * T_ + tb + row) << 6) + d0] = v;
        }
    } else {
        __syncthreads();
        u16 (*ldsT)[136] = (u16(*)[136])lds;
#pragma unroll
        for (int m = 0; m < 4; ++m)
#pragma unroll
            for (int n = 0; n < 4; ++n) {
                int cl = wc * 64 + n * 16 + l15;
                float bv = bias[c0 + cl];
                int rl = wr * 64 + m * 16 + l4 * 4;
#pragma unroll
                for (int j = 0; j < 4; ++j)
                    ldsT[cl][rl + j] = f2bf(acc[m][n][j] + bv);
            }
        __syncthreads();
        int b = r0 >> 11, tb = r0 & (T_ - 1);
#pragma unroll
        for (int it = 0; it < 8; ++it) {
            int chunk = tid + it * 256;
            int cl = chunk >> 4;
            int r8 = (chunk & 15) << 3;
            int cg = c0 + cl;
            int head = cg >> 6, d = cg & 63;
            uint4 v = *(const uint4*)&ldsT[cl][r8];
            *(uint4*)&dst_bf[((size_t)((b * NH_ + head) * DH_ + d) * T_) + tb + r8] = v;
        }
    }
}

// Fused QKV projection: grid (24,64). bx 0-7: Q, 8-15: K, 16-23: V.
__global__ __launch_bounds__(256) void gemm_qkv(
    const u16* __restrict__ qbf, const u16* __restrict__ vbf,
    const u16* __restrict__ Wqb, const u16* __restrict__ Wkb, const u16* __restrict__ Wvb,
    const float* __restrict__ bq, const float* __restrict__ bk, const float* __restrict__ bv,
    u16* __restrict__ Qd, u16* __restrict__ Kd, u16* __restrict__ Vtd)
{
    const int orig = blockIdx.y * 24 + blockIdx.x;
    const int swz = (orig & 7) * 192 + (orig >> 3);
    const int bx = swz % 24;
    const int by = swz / 24;
    const int seg = bx >> 3;
    const int r0 = by * BM;
    const int c0 = (bx & 7) * BN;

    if (seg == 0)
        gemm_core(qbf, Wqb, bq, Qd, nullptr, QSCALE, 0, r0, c0);
    else if (seg == 1)
        gemm_core(vbf, Wkb, bk, Kd, nullptr, 1.0f, 0, r0, c0);
    else
        gemm_core(vbf, Wvb, bv, Vtd, nullptr, 1.0f, 1, r0, c0);
}

// Output projection: grid (8,64). XCD swizzle chunk=64.
__global__ __launch_bounds__(256) void gemm_out(
    const u16* __restrict__ AO, const u16* __restrict__ Wob,
    const float* __restrict__ bo, float* __restrict__ out)
{
    const int orig = blockIdx.y * 8 + blockIdx.x;
    const int swz = (orig & 7) * 64 + (orig >> 3);
    const int bx = swz & 7;
    const int by = swz >> 3;
    gemm_core(AO, Wob, bo, nullptr, out, 1.0f, 2, by * BM, bx * BN);
}

#define KVB 64

// ================== KV-split partial attention ==================
// Each block: 256 q rows x HALF the kv range. Grid (16,64) = 1024 blocks.
// __launch_bounds__(256,2): cap VGPR at 128 (R6-proven: identical loop = 116).
// At <=128 VGPR the wave-slot bucket {64,128,256,512} allows 4 waves/SIMD,
// so 4 blocks/CU co-resident (LDS 4x32KB=128<=160KB) in ONE dispatch round.
// R8's default bound gave 180 VGPR -> 256-bucket -> 2 waves/SIMD -> regression.
__global__ __launch_bounds__(256, 2) void attnP(
    const u16* __restrict__ Q, const u16* __restrict__ K,
    const u16* __restrict__ Vt,
    float* __restrict__ OpA, float* __restrict__ OpB,
    float* __restrict__ LpA, float* __restrict__ LpB)
{
    __shared__ u16 lds[16384];   // 32KB: K0|V0|K1|V1, 8KB each
    char* const base = (char*)lds;

    const int tid = threadIdx.x;
    const int wid = tid >> 6;
    const int lane = tid & 63;
    const int l31 = lane & 31;
    const int hi = lane >> 5;

    // XCD swizzle: nwg=1024, chunk=128 => 8 whole heads per XCD
    const int orig = blockIdx.y * 16 + blockIdx.x;
    const int swz = (orig & 7) * 128 + (orig >> 3);
    const int bn = swz >> 4;
    const int rest = swz & 15;
    const int h = rest >> 3;                       // kv half
    const int q0w = (rest & 7) * 256 + wid * 64;   // wave's q base
    const int kv0 = h * (T_ / 2);

    const u16* Qb = Q + ((size_t)bn * T_ + q0w + l31) * DH_;
    const u16* Kb = K + (size_t)bn * T_ * DH_;
    const u16* Vb = Vt + (size_t)bn * DH_ * T_;

    bf16x8 qfa[4], qfb[4];
#pragma unroll
    for (int c = 0; c < 4; ++c) {
        qfa[c] = *(const bf16x8*)(Qb + c * 16 + hi * 8);
        qfb[c] = *(const bf16x8*)(Qb + 32 * DH_ + c * 16 + hi * 8);
    }

    f32x16 accO00, accO01, accO10, accO11;
#pragma unroll
    for (int r = 0; r < 16; ++r) {
        accO00[r] = 0.f; accO01[r] = 0.f;
        accO10[r] = 0.f; accO11[r] = 0.f;
    }
    float la = 0.f, lb = 0.f;

    const int srow = tid >> 3;
    const int scsw = (tid & 7) ^ (srow & 7);
    const int rowsw = l31 & 7;

    const u16* kSrc = Kb + (size_t)(kv0 + srow) * DH_ + scsw * 8;
    const u16* vSrc = Vb + (size_t)srow * T_ + kv0 + scsw * 8;

#define STAGE(dK, dV) do { \
    gload16(kSrc,            (dK) + tid * 16); \
    gload16(kSrc + 32 * DH_, (dK) + 4096 + tid * 16); \
    gload16(vSrc,            (dV) + tid * 16); \
    gload16(vSrc + 32 * T_,  (dV) + 4096 + tid * 16); \
    kSrc += KVB * DH_; vSrc += KVB; } while (0)

    char* const kb0 = base;
    char* const vb0 = base + 8192;
    char* const kb1 = base + 16384;
    char* const vb1 = base + 24576;

    auto process = [&](const char* kc, const char* vc) {
        f32x16 sA0, sA1, sB0, sB1;
#pragma unroll
        for (int r = 0; r < 16; ++r) { sA0[r] = 0.f; sA1[r] = 0.f; sB0[r] = 0.f; sB1[r] = 0.f; }
        __builtin_amdgcn_s_setprio(1);
#pragma unroll
        for (int c = 0; c < 4; ++c) {
            const int c16 = ((2 * c + hi) ^ rowsw) * 16;
            bf16x8 k0 = *(const bf16x8*)(kc + l31 * 128 + c16);
            bf16x8 k1 = *(const bf16x8*)(kc + 4096 + l31 * 128 + c16);
            sA0 = mfma32(k0, qfa[c], sA0);
            sA1 = mfma32(k1, qfa[c], sA1);
            sB0 = mfma32(k0, qfb[c], sB0);
            sB1 = mfma32(k1, qfb[c], sB1);
        }
        __builtin_amdgcn_s_setprio(0);

#pragma unroll
        for (int r = 0; r < 16; ++r) {
            sA0[r] = exp2_fast(sA0[r]);
            sA1[r] = exp2_fast(sA1[r]);
            sB0[r] = exp2_fast(sB0[r]);
            sB1[r] = exp2_fast(sB1[r]);
        }
        float ta = 0.f, tb2 = 0.f;
#pragma unroll
        for (int r = 0; r < 16; ++r) {
            ta  += sA0[r] + sA1[r];
            tb2 += sB0[r] + sB1[r];
        }
        la += ta; lb += tb2;

        unsigned w0a[8], w1a[8], w0b[8], w1b[8];
#pragma unroll
        for (int k2 = 0; k2 < 8; ++k2) {
            w0a[k2] = packbf2(sA0[2 * k2], sA0[2 * k2 + 1]);
            w1a[k2] = packbf2(sA1[2 * k2], sA1[2 * k2 + 1]);
            w0b[k2] = packbf2(sB0[2 * k2], sB0[2 * k2 + 1]);
            w1b[k2] = packbf2(sB1[2 * k2], sB1[2 * k2 + 1]);
        }
        plswap(w0a[0], w0a[2]); plswap(w0a[1], w0a[3]);
        plswap(w0a[4], w0a[6]); plswap(w0a[5], w0a[7]);
        plswap(w1a[0], w1a[2]); plswap(w1a[1], w1a[3]);
        plswap(w1a[4], w1a[6]); plswap(w1a[5], w1a[7]);
        plswap(w0b[0], w0b[2]); plswap(w0b[1], w0b[3]);
        plswap(w0b[4], w0b[6]); plswap(w0b[5], w0b[7]);
        plswap(w1b[0], w1b[2]); plswap(w1b[1], w1b[3]);
        plswap(w1b[4], w1b[6]); plswap(w1b[5], w1b[7]);

        __builtin_amdgcn_s_setprio(1);
#pragma unroll
        for (int ks = 0; ks < 4; ++ks) {
            union { unsigned w[4]; bf16x8 v; } pa, pb;
            const unsigned* sa_ = (ks < 2) ? w0a : w1a;
            const unsigned* sb_ = (ks < 2) ? w0b : w1b;
            const int o = (ks & 1) * 4;
            pa.w[0] = sa_[o + 0]; pa.w[1] = sa_[o + 1];
            pa.w[2] = sa_[o + 2]; pa.w[3] = sa_[o + 3];
            pb.w[0] = sb_[o + 0]; pb.w[1] = sb_[o + 1];
            pb.w[2] = sb_[o + 2]; pb.w[3] = sb_[o + 3];
            const int c16 = ((2 * ks + hi) ^ rowsw) * 16;
            bf16x8 v0f = *(const bf16x8*)(vc + l31 * 128 + c16);
            bf16x8 v1f = *(const bf16x8*)(vc + 4096 + l31 * 128 + c16);
            accO00 = mfma32(v0f, pa.v, accO00);
            accO01 = mfma32(v1f, pa.v, accO01);
            accO10 = mfma32(v0f, pb.v, accO10);
            accO11 = mfma32(v1f, pb.v, accO11);
        }
        __builtin_amdgcn_s_setprio(0);
    };

    STAGE(kb0, vb0);
    __syncthreads();

    const int NT = (T_ / 2) / KVB;   // 16
    for (int it = 0; it < NT; it += 2) {
        STAGE(kb1, vb1);
        process(kb0, vb0);
        __syncthreads();
        if (it + 2 < NT) STAGE(kb0, vb0);
        process(kb1, vb1);
        __syncthreads();
    }

    // ---- epilogue: store unnormalized partials, f32, q-contiguous ----
    la += __shfl_xor(la, 32);
    lb += __shfl_xor(lb, 32);

    float* Ob = (h ? OpB : OpA) + (size_t)bn * 64 * T_;
    float* Lb2 = (h ? LpB : LpA) + (size_t)bn * T_;
#pragma unroll
    for (int n = 0; n < 2; ++n)
#pragma unroll
        for (int r = 0; r < 16; ++r) {
            int d = n * 32 + (r & 3) + 8 * (r >> 2) + 4 * hi;
            Ob[(size_t)d * T_ + q0w + l31]      = (n == 0 ? accO00[r] : accO01[r]);
            Ob[(size_t)d * T_ + q0w + 32 + l31] = (n == 0 ? accO10[r] : accO11[r]);
        }
    if (hi == 0) {
        Lb2[q0w + l31]      = la;
        Lb2[q0w + 32 + l31] = lb;
    }
#undef STAGE
}

// ================== combine partials -> AO bf16 ==================
// grid (32 qblocks, 64 bn). O = (O1+O2)/(L1+L2), transpose [d][q]->[q][d].
__global__ __launch_bounds__(256) void combineO(
    const float* __restrict__ OpA, const float* __restrict__ OpB,
    const float* __restrict__ LpA, const float* __restrict__ LpB,
    u16* __restrict__ AO)
{
    __shared__ float ot[64][65];
    __shared__ float ls[64];

    const int tid = threadIdx.x;
    const int bn = blockIdx.y;
    const int q0 = blockIdx.x * 64;
    const int b = bn >> 4, head = bn & 15;

    const size_t obase = (size_t)bn * 64 * T_;
    const int qi = tid & 63;
    const int d0 = tid >> 6;

    if (tid < 64)
        ls[tid] = 1.f / (LpA[(size_t)bn * T_ + q0 + tid] + LpB[(size_t)bn * T_ + q0 + tid]);
#pragma unroll
    for (int d = 0; d < 16; ++d) {
        int dd = d0 + d * 4;
        ot[dd][qi] = OpA[obase + (size_t)dd * T_ + q0 + qi]
                   + OpB[obase + (size_t)dd * T_ + q0 + qi];
    }
    __syncthreads();
#pragma unroll
    for (int itq = 0; itq < 2; ++itq) {
        int q = itq * 32 + (tid >> 3);
        int dc = (tid & 7) * 8;
        float inv = ls[q];
        union { u16 h[8]; uint4 v; } o;
#pragma unroll
        for (int j = 0; j < 8; ++j) o.h[j] = f2bf(ot[dc + j][q] * inv);
        *(uint4*)&AO[(size_t)(b * T_ + q0 + q) * (NH_ * DH_) + head * DH_ + dc] = o.v;
    }
}

// ================== fallback single-kernel attention (R6, 82us) ==================
__global__ __launch_bounds__(256, 2) void attn64(
    const u16* __restrict__ Q, const u16* __restrict__ K,
    const u16* __restrict__ Vt, u16* __restrict__ AO)
{
    __shared__ u16 lds[16384];
    char* const base = (char*)lds;

    const int tid = threadIdx.x;
    const int wid = tid >> 6;
    const int lane = tid & 63;
    const int l31 = lane & 31;
    const int hi = lane >> 5;

    const int orig = blockIdx.y * 8 + blockIdx.x;
    const int swz = (orig & 7) * 64 + (orig >> 3);
    const int bn = swz >> 3;
    const int q0w = (swz & 7) * 256 + wid * 64;
    const int b = bn >> 4, head = bn & 15;

    const u16* Qb = Q + ((size_t)bn * T_ + q0w + l31) * DH_;
    const u16* Kb = K + (size_t)bn * T_ * DH_;
    const u16* Vb = Vt + (size_t)bn * DH_ * T_;

    bf16x8 qfa[4], qfb[4];
#pragma unroll
    for (int c = 0; c < 4; ++c) {
        qfa[c] = *(const bf16x8*)(Qb + c * 16 + hi * 8);
        qfb[c] = *(const bf16x8*)(Qb + 32 * DH_ + c * 16 + hi * 8);
    }

    f32x16 accO00, accO01, accO10, accO11;
#pragma unroll
    for (int r = 0; r < 16; ++r) {
        accO00[r] = 0.f; accO01[r] = 0.f;
        accO10[r] = 0.f; accO11[r] = 0.f;
    }
    float la = 0.f, lb = 0.f;

    const int srow = tid >> 3;
    const int scsw = (tid & 7) ^ (srow & 7);
    const int rowsw = l31 & 7;

    const u16* kSrc = Kb + (size_t)srow * DH_ + scsw * 8;
    const u16* vSrc = Vb + (size_t)srow * T_ + scsw * 8;

#define STAGE(dK, dV) do { \
    gload16(kSrc,            (dK) + tid * 16); \
    gload16(kSrc + 32 * DH_, (dK) + 4096 + tid * 16); \
    gload16(vSrc,            (dV) + tid * 16); \
    gload16(vSrc + 32 * T_,  (dV) + 4096 + tid * 16); \
    kSrc += KVB * DH_; vSrc += KVB; } while (0)

    char* const kb0 = base;
    char* const vb0 = base + 8192;
    char* const kb1 = base + 16384;
    char* const vb1 = base + 24576;

    auto process = [&](const char* kc, const char* vc) {
        f32x16 sA0, sA1, sB0, sB1;
#pragma unroll
        for (int r = 0; r < 16; ++r) { sA0[r] = 0.f; sA1[r] = 0.f; sB0[r] = 0.f; sB1[r] = 0.f; }
        __builtin_amdgcn_s_setprio(1);
#pragma unroll
        for (int c = 0; c < 4; ++c) {
            const int c16 = ((2 * c + hi) ^ rowsw) * 16;
            bf16x8 k0 = *(const bf16x8*)(kc + l31 * 128 + c16);
            bf16x8 k1 = *(const bf16x8*)(kc + 4096 + l31 * 128 + c16);
            sA0 = mfma32(k0, qfa[c], sA0);
            sA1 = mfma32(k1, qfa[c], sA1);
            sB0 = mfma32(k0, qfb[c], sB0);
            sB1 = mfma32(k1, qfb[c], sB1);
        }
        __builtin_amdgcn_s_setprio(0);

#pragma unroll
        for (int r = 0; r < 16; ++r) {
            sA0[r] = exp2_fast(sA0[r]);
            sA1[r] = exp2_fast(sA1[r]);
            sB0[r] = exp2_fast(sB0[r]);
            sB1[r] = exp2_fast(sB1[r]);
        }
        float ta = 0.f, tb2 = 0.f;
#pragma unroll
        for (int r = 0; r < 16; ++r) {
            ta  += sA0[r] + sA1[r];
            tb2 += sB0[r] + sB1[r];
        }
        la += ta; lb += tb2;

        unsigned w0a[8], w1a[8], w0b[8], w1b[8];
#pragma unroll
        for (int k2 = 0; k2 < 8; ++k2) {
            w0a[k2] = packbf2(sA0[2 * k2], sA0[2 * k2 + 1]);
            w1a[k2] = packbf2(sA1[2 * k2], sA1[2 * k2 + 1]);
            w0b[k2] = packbf2(sB0[2 * k2], sB0[2 * k2 + 1]);
            w1b[k2] = packbf2(sB1[2 * k2], sB1[2 * k2 + 1]);
        }
        plswap(w0a[0], w0a[2]); plswap(w0a[1], w0a[3]);
        plswap(w0a[4], w0a[6]); plswap(w0a[5], w0a[7]);
        plswap(w1a[0], w1a[2]); plswap(w1a[1], w1a[3]);
        plswap(w1a[4], w1a[6]); plswap(w1a[5], w1a[7]);
        plswap(w0b[0], w0b[2]); plswap(w0b[1], w0b[3]);
        plswap(w0b[4], w0b[6]); plswap(w0b[5], w0b[7]);
        plswap(w1b[0], w1b[2]); plswap(w1b[1], w1b[3]);
        plswap(w1b[4], w1b[6]); plswap(w1b[5], w1b[7]);

        __builtin_amdgcn_s_setprio(1);
#pragma unroll
        for (int ks = 0; ks < 4; ++ks) {
            union { unsigned w[4]; bf16x8 v; } pa, pb;
            const unsigned* sa_ = (ks < 2) ? w0a : w1a;
            const unsigned* sb_ = (ks < 2) ? w0b : w1b;
            const int o = (ks & 1) * 4;
            pa.w[0] = sa_[o + 0]; pa.w[1] = sa_[o + 1];
            pa.w[2] = sa_[o + 2]; pa.w[3] = sa_[o + 3];
            pb.w[0] = sb_[o + 0]; pb.w[1] = sb_[o + 1];
            pb.w[2] = sb_[o + 2]; pb.w[3] = sb_[o + 3];
            const int c16 = ((2 * ks + hi) ^ rowsw) * 16;
            bf16x8 v0f = *(const bf16x8*)(vc + l31 * 128 + c16);
            bf16x8 v1f = *(const bf16x8*)(vc + 4096 + l31 * 128 + c16);
            accO00 = mfma32(v0f, pa.v, accO00);
            accO01 = mfma32(v1f, pa.v, accO01);
            accO10 = mfma32(v0f, pb.v, accO10);
            accO11 = mfma32(v1f, pb.v, accO11);
        }
        __builtin_amdgcn_s_setprio(0);
    };

    STAGE(kb0, vb0);
    __syncthreads();

    for (int it = 0; it < T_ / KVB; it += 2) {
        STAGE(kb1, vb1);
        process(kb0, vb0);
        __syncthreads();
        if (it + 2 < T_ / KVB) STAGE(kb0, vb0);
        process(kb1, vb1);
        __syncthreads();
    }

    la += __shfl_xor(la, 32);
    lb += __shfl_xor(lb, 32);

    char* myO = base + wid * 8192;
    float inva = 1.f / la;
    float invb = 1.f / lb;
#pragma unroll
    for (int n = 0; n < 2; ++n)
#pragma unroll
        for (int r = 0; r < 16; ++r) {
            int d = n * 32 + (r & 3) + 8 * (r >> 2) + 4 * hi;
            int c16 = (d >> 3) ^ rowsw;
            float va = (n == 0 ? accO00[r] : accO01[r]) * inva;
            float vb2 = (n == 0 ? accO10[r] : accO11[r]) * invb;
            *(u16*)(myO + l31 * 128 + c16 * 16 + (d & 7) * 2) = f2bf(va);
            *(u16*)(myO + (32 + l31) * 128 + c16 * 16 + (d & 7) * 2) = f2bf(vb2);
        }
    asm volatile("s_waitcnt lgkmcnt(0)" ::: "memory");
#pragma unroll
    for (int it = 0; it < 8; ++it) {
        int id = lane + it * 64;
        int row = id >> 3;
        int c = id & 7;
        int c16s = c ^ (row & 7);
        uint4 val = *(const uint4*)(myO + row * 128 + c16s * 16);
        *(uint4*)&AO[(size_t)(b * T_ + q0w + row) * (NH_ * DH_) + head * DH_ + c * 8] = val;
    }
#undef STAGE
}

// ---------------- host launch ----------------
extern "C" void kernel_launch(void* const* d_in, const int* in_sizes, int n_in,
                              void* d_out, int out_size, void* d_ws, size_t ws_size,
                              hipStream_t stream)
{
    const float* query = (const float*)d_in[0];
    const float* value = (const float*)d_in[1];
    const float* Wq = (const float*)d_in[2];
    const float* bq = (const float*)d_in[3];
    const float* Wk = (const float*)d_in[4];
    const float* bk = (const float*)d_in[5];
    const float* Wv = (const float*)d_in[6];
    const float* bv = (const float*)d_in[7];
    const float* Wo = (const float*)d_in[8];
    const float* bo = (const float*)d_in[9];
    float* out = (float*)d_out;

    u16* ws = (u16*)d_ws;
    char* wsb = (char*)d_ws;
    const size_t E8M = (size_t)8 << 20;
    const size_t MB = (size_t)1 << 20;
    u16* qbf = ws;                    // [0, 16MB)
    u16* vbf = ws + E8M;              // [16, 32)
    u16* Wqb = ws + 2 * E8M;          // [32, 34)
    u16* Wkb = Wqb + (1u << 20);      // [34, 36)
    u16* Wvb = Wkb + (1u << 20);      // [36, 38)
    u16* Wob = Wvb + (1u << 20);      // [38, 40)
    u16* Qd  = Wob + (1u << 20);      // [40, 56)
    u16* Kd  = Qd + E8M;              // [56, 72)
    u16* Vtd = Kd + E8M;              // [72, 88)
    u16* AO  = Vtd + E8M;             // [88, 104)
    // KV-split partials (reuse dead regions + extend):
    float* OpA = (float*)wsb;                 // [0, 32) - qbf/vbf dead after gemm_qkv
    float* LpA = (float*)(wsb + 32 * MB);     // [32, 32.5) - Wqb dead
    float* LpB = (float*)(wsb + 32 * MB + 512 * 1024);  // [32.5, 33)
    float* OpB = (float*)(wsb + 104 * MB);    // [104, 136) - extension
    const size_t NEED = 136 * MB;

    const int nBig = (B_ * T_ * H_) / 4;
    const int nW   = (KDIM * KDIM) / 4;
    f2bf_hex<<<dim3(512, 6), 256, 0, stream>>>(
        query, qbf, nBig, value, vbf, nBig,
        Wq, Wqb, nW, Wk, Wkb, nW, Wv, Wvb, nW, Wo, Wob, nW);

    gemm_qkv<<<dim3(24, 64), 256, 0, stream>>>(qbf, vbf, Wqb, Wkb, Wvb,
                                               bq, bk, bv, Qd, Kd, Vtd);

    if (ws_size >= NEED) {
        attnP<<<dim3(16, 64), 256, 0, stream>>>(Qd, Kd, Vtd, OpA, OpB, LpA, LpB);
        combineO<<<dim3(32, 64), 256, 0, stream>>>(OpA, OpB, LpA, LpB, AO);
    } else {
        attn64<<<dim3(8, 64), 256, 0, stream>>>(Qd, Kd, Vtd, AO);
    }

    gemm_out<<<dim3(8, 64), 256, 0, stream>>>(AO, Wob, bo, out);
}

// Round 11
// 183.014 us; speedup vs baseline: 4.2708x; 1.1389x over previous
//
#include <hip/hip_runtime.h>
#include <cstdint>
#include <cstddef>

typedef unsigned short u16;
typedef __bf16 bf16x8 __attribute__((ext_vector_type(8)));
typedef __bf16 bf16x2 __attribute__((ext_vector_type(2)));
typedef float f32x4 __attribute__((ext_vector_type(4)));
typedef float f32x16 __attribute__((ext_vector_type(16)));

#define B_   4
#define T_   2048
#define H_   1024
#define NH_  16
#define DH_  64
#define M_   (B_ * T_)      // 8192
#define KDIM 1024
// SCALE * log2(e): scores computed directly in log2 domain
#define QSCALE 0.18033688011112042f

#define BM 128
#define BN 128
#define BK 32

__device__ __forceinline__ u16 f2bf(float f) {
    unsigned u = __float_as_uint(f);
    unsigned r = (u + 0x7fffu + ((u >> 16) & 1u)) >> 16;  // RNE
    return (u16)r;
}

__device__ __forceinline__ unsigned packbf2(float a, float b) {
    bf16x2 v = { (__bf16)a, (__bf16)b };   // compiler emits v_cvt_pk_bf16_f32
    return __builtin_bit_cast(unsigned, v);
}

__device__ __forceinline__ float exp2_fast(float x) {
#if __has_builtin(__builtin_amdgcn_exp2f)
    return __builtin_amdgcn_exp2f(x);
#else
    return exp2f(x);
#endif
}

// in-place half-wave swap
__device__ __forceinline__ void plswap(unsigned &a, unsigned &b) {
#if __has_builtin(__builtin_amdgcn_permlane32_swap)
    auto r = __builtin_amdgcn_permlane32_swap(a, b, false, false);
    a = (unsigned)r[0]; b = (unsigned)r[1];
#else
    int hi = (threadIdx.x & 32);
    unsigned x = (unsigned)__shfl_xor((int)(hi ? b : a), 32);
    unsigned na = hi ? x : a;
    unsigned nb = hi ? b : x;
    a = na; b = nb;
#endif
}

__device__ __forceinline__ void gload16(const void* g, void* l) {
    __builtin_amdgcn_global_load_lds(
        (const __attribute__((address_space(1))) unsigned int*)g,
        (__attribute__((address_space(3))) unsigned int*)l,
        16, 0, 0);
}

__device__ __forceinline__ f32x16 mfma32(bf16x8 a, bf16x8 b, f32x16 c) {
    return __builtin_amdgcn_mfma_f32_32x32x16_bf16(a, b, c, 0, 0, 0);
}

// ---------------- fp32 -> bf16 converts (single launch, 6 jobs) ----------------
__global__ __launch_bounds__(256) void f2bf_hex(
    const float* s0, u16* d0, int n0, const float* s1, u16* d1, int n1,
    const float* s2, u16* d2, int n2, const float* s3, u16* d3, int n3,
    const float* s4, u16* d4, int n4j, const float* s5, u16* d5, int n5)
{
    const float* s; u16* d; int n;
    switch (blockIdx.y) {
        case 0: s = s0; d = d0; n = n0; break;
        case 1: s = s1; d = d1; n = n1; break;
        case 2: s = s2; d = d2; n = n2; break;
        case 3: s = s3; d = d3; n = n3; break;
        case 4: s = s4; d = d4; n = n4j; break;
        default: s = s5; d = d5; n = n5; break;
    }
    int i = blockIdx.x * blockDim.x + threadIdx.x;
    int stride = gridDim.x * blockDim.x;
    for (; i < n; i += stride) {
        float4 f = reinterpret_cast<const float4*>(s)[i];
        ushort4 o;
        o.x = f2bf(f.x); o.y = f2bf(f.y); o.z = f2bf(f.z); o.w = f2bf(f.w);
        reinterpret_cast<ushort4*>(d)[i] = o;
    }
}

// ---------------- 128x128 bf16 GEMM core  C = X * W^T ----------------
// T3/T4: TRIPLE-buffered staging with counted vmcnt. Per K-step:
//   s_waitcnt vmcnt(4) lgkmcnt(0); s_barrier;   // tile kt landed (its 4 loads
//       were issued 2 steps ago; only kt+1's 4 may remain in flight);
//       lgkmcnt(0): my ds_reads of tile kt-1 done -> safe for anyone to
//       overwrite buf[(kt-1)%3] after the barrier.
//   STAGEG(buf[(kt+2)%3], kt+2);                // prefetch stays in flight
//   compute(buf[kt%3])
// Tail peeled with vmcnt(0). Loads issued 2 K-steps ahead => HBM latency
// fully hidden; no full drain at barriers (the m97-structure ~20% stall).
__device__ __forceinline__ void gemm_core(
    const u16* __restrict__ X, const u16* __restrict__ W,
    const float* __restrict__ bias,
    u16* __restrict__ dst_bf, float* __restrict__ dst_f,
    float scale, int mode, int r0, int c0)
{
    __shared__ u16 lds[24576];   // 49,152 B: 3 staging buffers x 16KB
    char* const base = (char*)lds;

    const int tid = threadIdx.x;
    const int wid = tid >> 6;
    const int l15 = tid & 15;
    const int l4  = (tid & 63) >> 4;
    const int wr = wid >> 1, wc = wid & 1;

    const u16* gA = X + (size_t)(r0 + (tid >> 2)) * KDIM + (tid & 3) * 8;
    const u16* gB = W + (size_t)(c0 + (tid >> 2)) * KDIM + (tid & 3) * 8;

    f32x4 acc[4][4];
#pragma unroll
    for (int m = 0; m < 4; ++m)
#pragma unroll
        for (int n = 0; n < 4; ++n) acc[m][n] = (f32x4){0.f, 0.f, 0.f, 0.f};

    const int arow = wr * 64 + l15;
    const int brow = wc * 64 + l15;

#define STAGEG(p, kt) do { \
    const u16* pa_ = gA + (kt) * BK; \
    const u16* pb_ = gB + (kt) * BK; \
    char* dA_ = base + (p) * 16384 + wid * 1024; \
    char* dB_ = dA_ + 8192; \
    gload16(pa_, dA_); gload16(pa_ + 64 * KDIM, dA_ + 4096); \
    gload16(pb_, dB_); gload16(pb_ + 64 * KDIM, dB_ + 4096); } while (0)

#define COMPUTE(p) do { \
    const char* bufp = base + (p) * 16384; \
    bf16x8 a[4], b[4]; \
    _Pragma("unroll") \
    for (int m = 0; m < 4; ++m) \
        a[m] = *(const bf16x8*)(bufp + (arow + m * 16) * 64 + l4 * 16); \
    _Pragma("unroll") \
    for (int n = 0; n < 4; ++n) \
        b[n] = *(const bf16x8*)(bufp + 8192 + (brow + n * 16) * 64 + l4 * 16); \
    _Pragma("unroll") \
    for (int m = 0; m < 4; ++m) \
        _Pragma("unroll") \
        for (int n = 0; n < 4; ++n) \
            acc[m][n] = __builtin_amdgcn_mfma_f32_16x16x32_bf16(a[m], b[n], acc[m][n], 0, 0, 0); \
    } while (0)

    STAGEG(0, 0);
    STAGEG(1, 1);

    int p = 0;
    for (int kt = 0; kt < KDIM / BK - 1; ++kt) {
        asm volatile("s_waitcnt vmcnt(4) lgkmcnt(0)\n\ts_barrier" ::: "memory");
        if (kt + 2 < KDIM / BK) {
            int fp = p + 2; if (fp >= 3) fp -= 3;
            STAGEG(fp, kt + 2);
        }
        COMPUTE(p);
        ++p; if (p == 3) p = 0;
    }
    asm volatile("s_waitcnt vmcnt(0) lgkmcnt(0)\n\ts_barrier" ::: "memory");
    COMPUTE(p);
#undef COMPUTE
#undef STAGEG

    if (mode == 2) {
#pragma unroll
        for (int m = 0; m < 4; ++m)
#pragma unroll
            for (int n = 0; n < 4; ++n) {
                int cg = c0 + wc * 64 + n * 16 + l15;
                float bv = bias[cg];
                int rg = r0 + wr * 64 + m * 16 + l4 * 4;
#pragma unroll
                for (int j = 0; j < 4; ++j)
                    dst_f[(size_t)(rg + j) * H_ + cg] = acc[m][n][j] + bv;
            }
    } else if (mode == 0) {
        // stage C row-major in LDS ([128][136] u16), 16B coalesced stores
        __syncthreads();
        u16 (*ldsR)[136] = (u16(*)[136])lds;
#pragma unroll
        for (int m = 0; m < 4; ++m)
#pragma unroll
            for (int n = 0; n < 4; ++n) {
                int cl = wc * 64 + n * 16 + l15;
                float bv = bias[c0 + cl];
                int rl = wr * 64 + m * 16 + l4 * 4;
#pragma unroll
                for (int j = 0; j < 4; ++j)
                    ldsR[rl + j][cl] = f2bf((acc[m][n][j] + bv) * scale);
            }
        __syncthreads();
        int b2 = r0 >> 11, tb = r0 & (T_ - 1);
#pragma unroll
        for (int it = 0; it < 8; ++it) {
            int id = tid + it * 256;
            int row = id >> 4;
            int ch = id & 15;
            int head = (c0 >> 6) + (ch >> 3);
            int d0 = (ch & 7) * 8;
            uint4 v = *(const uint4*)&ldsR[row][ch * 8];
            *(uint4*)&dst_bf[(((size_t)(b2 * NH_ + head) * T_ + tb + row) << 6) + d0] = v;
        }
    } else {
        __syncthreads();
        u16 (*ldsT)[136] = (u16(*)[136])lds;
#pragma unroll
        for (int m = 0; m < 4; ++m)
#pragma unroll
            for (int n = 0; n < 4; ++n) {
                int cl = wc * 64 + n * 16 + l15;
                float bv = bias[c0 + cl];
                int rl = wr * 64 + m * 16 + l4 * 4;
#pragma unroll
                for (int j = 0; j < 4; ++j)
                    ldsT[cl][rl + j] = f2bf(acc[m][n][j] + bv);
            }
        __syncthreads();
        int b = r0 >> 11, tb = r0 & (T_ - 1);
#pragma unroll
        for (int it = 0; it < 8; ++it) {
            int chunk = tid + it * 256;
            int cl = chunk >> 4;
            int r8 = (chunk & 15) << 3;
            int cg = c0 + cl;
            int head = cg >> 6, d = cg & 63;
            uint4 v = *(const uint4*)&ldsT[cl][r8];
            *(uint4*)&dst_bf[((size_t)((b * NH_ + head) * DH_ + d) * T_) + tb + r8] = v;
        }
    }
}

// Fused QKV projection: grid (24,64). bx 0-7: Q, 8-15: K, 16-23: V.
__global__ __launch_bounds__(256) void gemm_qkv(
    const u16* __restrict__ qbf, const u16* __restrict__ vbf,
    const u16* __restrict__ Wqb, const u16* __restrict__ Wkb, const u16* __restrict__ Wvb,
    const float* __restrict__ bq, const float* __restrict__ bk, const float* __restrict__ bv,
    u16* __restrict__ Qd, u16* __restrict__ Kd, u16* __restrict__ Vtd)
{
    const int orig = blockIdx.y * 24 + blockIdx.x;
    const int swz = (orig & 7) * 192 + (orig >> 3);
    const int bx = swz % 24;
    const int by = swz / 24;
    const int seg = bx >> 3;
    const int r0 = by * BM;
    const int c0 = (bx & 7) * BN;

    if (seg == 0)
        gemm_core(qbf, Wqb, bq, Qd, nullptr, QSCALE, 0, r0, c0);
    else if (seg == 1)
        gemm_core(vbf, Wkb, bk, Kd, nullptr, 1.0f, 0, r0, c0);
    else
        gemm_core(vbf, Wvb, bv, Vtd, nullptr, 1.0f, 1, r0, c0);
}

// Output projection: grid (8,64). XCD swizzle chunk=64.
__global__ __launch_bounds__(256) void gemm_out(
    const u16* __restrict__ AO, const u16* __restrict__ Wob,
    const float* __restrict__ bo, float* __restrict__ out)
{
    const int orig = blockIdx.y * 8 + blockIdx.x;
    const int swz = (orig & 7) * 64 + (orig >> 3);
    const int bx = swz & 7;
    const int by = swz >> 3;
    gemm_core(AO, Wob, bo, nullptr, out, 1.0f, 2, by * BM, bx * BN);
}

// ---------------- flash attention: swapped-operand 32x32, Q-width 64 ----
// R6-proven 82us kernel. Unified-register note (R8/R9 lesson): arch VGPR 116
// + 64 acc = 180 unified -> 2 waves/SIMD bucket; this is the structure's
// occupancy floor (throughput-limited at MFMA 35% + VALU 39% concurrent).
#define KVB 64

__global__ __launch_bounds__(256, 2) void attn64(
    const u16* __restrict__ Q, const u16* __restrict__ K,
    const u16* __restrict__ Vt, u16* __restrict__ AO)
{
    __shared__ u16 lds[16384];
    char* const base = (char*)lds;

    const int tid = threadIdx.x;
    const int wid = tid >> 6;
    const int lane = tid & 63;
    const int l31 = lane & 31;
    const int hi = lane >> 5;

    const int orig = blockIdx.y * 8 + blockIdx.x;
    const int swz = (orig & 7) * 64 + (orig >> 3);
    const int bn = swz >> 3;
    const int q0w = (swz & 7) * 256 + wid * 64;
    const int b = bn >> 4, head = bn & 15;

    const u16* Qb = Q + ((size_t)bn * T_ + q0w + l31) * DH_;
    const u16* Kb = K + (size_t)bn * T_ * DH_;
    const u16* Vb = Vt + (size_t)bn * DH_ * T_;

    bf16x8 qfa[4], qfb[4];
#pragma unroll
    for (int c = 0; c < 4; ++c) {
        qfa[c] = *(const bf16x8*)(Qb + c * 16 + hi * 8);
        qfb[c] = *(const bf16x8*)(Qb + 32 * DH_ + c * 16 + hi * 8);
    }

    f32x16 accO00, accO01, accO10, accO11;
#pragma unroll
    for (int r = 0; r < 16; ++r) {
        accO00[r] = 0.f; accO01[r] = 0.f;
        accO10[r] = 0.f; accO11[r] = 0.f;
    }
    float la = 0.f, lb = 0.f;

    const int srow = tid >> 3;
    const int scsw = (tid & 7) ^ (srow & 7);
    const int rowsw = l31 & 7;

    const u16* kSrc = Kb + (size_t)srow * DH_ + scsw * 8;
    const u16* vSrc = Vb + (size_t)srow * T_ + scsw * 8;

#define STAGE(dK, dV) do { \
    gload16(kSrc,            (dK) + tid * 16); \
    gload16(kSrc + 32 * DH_, (dK) + 4096 + tid * 16); \
    gload16(vSrc,            (dV) + tid * 16); \
    gload16(vSrc + 32 * T_,  (dV) + 4096 + tid * 16); \
    kSrc += KVB * DH_; vSrc += KVB; } while (0)

    char* const kb0 = base;
    char* const vb0 = base + 8192;
    char* const kb1 = base + 16384;
    char* const vb1 = base + 24576;

    auto process = [&](const char* kc, const char* vc) {
        f32x16 sA0, sA1, sB0, sB1;
#pragma unroll
        for (int r = 0; r < 16; ++r) { sA0[r] = 0.f; sA1[r] = 0.f; sB0[r] = 0.f; sB1[r] = 0.f; }
        __builtin_amdgcn_s_setprio(1);
#pragma unroll
        for (int c = 0; c < 4; ++c) {
            const int c16 = ((2 * c + hi) ^ rowsw) * 16;
            bf16x8 k0 = *(const bf16x8*)(kc + l31 * 128 + c16);
            bf16x8 k1 = *(const bf16x8*)(kc + 4096 + l31 * 128 + c16);
            sA0 = mfma32(k0, qfa[c], sA0);
            sA1 = mfma32(k1, qfa[c], sA1);
            sB0 = mfma32(k0, qfb[c], sB0);
            sB1 = mfma32(k1, qfb[c], sB1);
        }
        __builtin_amdgcn_s_setprio(0);

#pragma unroll
        for (int r = 0; r < 16; ++r) {
            sA0[r] = exp2_fast(sA0[r]);
            sA1[r] = exp2_fast(sA1[r]);
            sB0[r] = exp2_fast(sB0[r]);
            sB1[r] = exp2_fast(sB1[r]);
        }
        float ta = 0.f, tb2 = 0.f;
#pragma unroll
        for (int r = 0; r < 16; ++r) {
            ta  += sA0[r] + sA1[r];
            tb2 += sB0[r] + sB1[r];
        }
        la += ta; lb += tb2;

        unsigned w0a[8], w1a[8], w0b[8], w1b[8];
#pragma unroll
        for (int k2 = 0; k2 < 8; ++k2) {
            w0a[k2] = packbf2(sA0[2 * k2], sA0[2 * k2 + 1]);
            w1a[k2] = packbf2(sA1[2 * k2], sA1[2 * k2 + 1]);
            w0b[k2] = packbf2(sB0[2 * k2], sB0[2 * k2 + 1]);
            w1b[k2] = packbf2(sB1[2 * k2], sB1[2 * k2 + 1]);
        }
        plswap(w0a[0], w0a[2]); plswap(w0a[1], w0a[3]);
        plswap(w0a[4], w0a[6]); plswap(w0a[5], w0a[7]);
        plswap(w1a[0], w1a[2]); plswap(w1a[1], w1a[3]);
        plswap(w1a[4], w1a[6]); plswap(w1a[5], w1a[7]);
        plswap(w0b[0], w0b[2]); plswap(w0b[1], w0b[3]);
        plswap(w0b[4], w0b[6]); plswap(w0b[5], w0b[7]);
        plswap(w1b[0], w1b[2]); plswap(w1b[1], w1b[3]);
        plswap(w1b[4], w1b[6]); plswap(w1b[5], w1b[7]);

        __builtin_amdgcn_s_setprio(1);
#pragma unroll
        for (int ks = 0; ks < 4; ++ks) {
            union { unsigned w[4]; bf16x8 v; } pa, pb;
            const unsigned* sa_ = (ks < 2) ? w0a : w1a;
            const unsigned* sb_ = (ks < 2) ? w0b : w1b;
            const int o = (ks & 1) * 4;
            pa.w[0] = sa_[o + 0]; pa.w[1] = sa_[o + 1];
            pa.w[2] = sa_[o + 2]; pa.w[3] = sa_[o + 3];
            pb.w[0] = sb_[o + 0]; pb.w[1] = sb_[o + 1];
            pb.w[2] = sb_[o + 2]; pb.w[3] = sb_[o + 3];
            const int c16 = ((2 * ks + hi) ^ rowsw) * 16;
            bf16x8 v0f = *(const bf16x8*)(vc + l31 * 128 + c16);
            bf16x8 v1f = *(const bf16x8*)(vc + 4096 + l31 * 128 + c16);
            accO00 = mfma32(v0f, pa.v, accO00);
            accO01 = mfma32(v1f, pa.v, accO01);
            accO10 = mfma32(v0f, pb.v, accO10);
            accO11 = mfma32(v1f, pb.v, accO11);
        }
        __builtin_amdgcn_s_setprio(0);
    };

    STAGE(kb0, vb0);
    __syncthreads();

    for (int it = 0; it < T_ / KVB; it += 2) {
        STAGE(kb1, vb1);
        process(kb0, vb0);
        __syncthreads();
        if (it + 2 < T_ / KVB) STAGE(kb0, vb0);
        process(kb1, vb1);
        __syncthreads();
    }

    la += __shfl_xor(la, 32);
    lb += __shfl_xor(lb, 32);

    char* myO = base + wid * 8192;
    float inva = 1.f / la;
    float invb = 1.f / lb;
#pragma unroll
    for (int n = 0; n < 2; ++n)
#pragma unroll
        for (int r = 0; r < 16; ++r) {
            int d = n * 32 + (r & 3) + 8 * (r >> 2) + 4 * hi;
            int c16 = (d >> 3) ^ rowsw;
            float va = (n == 0 ? accO00[r] : accO01[r]) * inva;
            float vb2 = (n == 0 ? accO10[r] : accO11[r]) * invb;
            *(u16*)(myO + l31 * 128 + c16 * 16 + (d & 7) * 2) = f2bf(va);
            *(u16*)(myO + (32 + l31) * 128 + c16 * 16 + (d & 7) * 2) = f2bf(vb2);
        }
    asm volatile("s_waitcnt lgkmcnt(0)" ::: "memory");
#pragma unroll
    for (int it = 0; it < 8; ++it) {
        int id = lane + it * 64;
        int row = id >> 3;
        int c = id & 7;
        int c16s = c ^ (row & 7);
        uint4 val = *(const uint4*)(myO + row * 128 + c16s * 16);
        *(uint4*)&AO[(size_t)(b * T_ + q0w + row) * (NH_ * DH_) + head * DH_ + c * 8] = val;
    }
#undef STAGE
}

// ---------------- host launch ----------------
extern "C" void kernel_launch(void* const* d_in, const int* in_sizes, int n_in,
                              void* d_out, int out_size, void* d_ws, size_t ws_size,
                              hipStream_t stream)
{
    const float* query = (const float*)d_in[0];
    const float* value = (const float*)d_in[1];
    const float* Wq = (const float*)d_in[2];
    const float* bq = (const float*)d_in[3];
    const float* Wk = (const float*)d_in[4];
    const float* bk = (const float*)d_in[5];
    const float* Wv = (const float*)d_in[6];
    const float* bv = (const float*)d_in[7];
    const float* Wo = (const float*)d_in[8];
    const float* bo = (const float*)d_in[9];
    float* out = (float*)d_out;

    u16* ws = (u16*)d_ws;
    const size_t E8M = (size_t)8 << 20;
    u16* qbf = ws;
    u16* vbf = ws + E8M;
    u16* Wqb = ws + 2 * E8M;
    u16* Wkb = Wqb + (1u << 20);
    u16* Wvb = Wkb + (1u << 20);
    u16* Wob = Wvb + (1u << 20);
    u16* Qd  = Wob + (1u << 20);
    u16* Kd  = Qd + E8M;
    u16* Vtd = Kd + E8M;
    u16* AO  = Vtd + E8M;

    const int nBig = (B_ * T_ * H_) / 4;
    const int nW   = (KDIM * KDIM) / 4;
    f2bf_hex<<<dim3(512, 6), 256, 0, stream>>>(
        query, qbf, nBig, value, vbf, nBig,
        Wq, Wqb, nW, Wk, Wkb, nW, Wv, Wvb, nW, Wo, Wob, nW);

    gemm_qkv<<<dim3(24, 64), 256, 0, stream>>>(qbf, vbf, Wqb, Wkb, Wvb,
                                               bq, bk, bv, Qd, Kd, Vtd);

    attn64<<<dim3(8, 64), 256, 0, stream>>>(Qd, Kd, Vtd, AO);

    gemm_out<<<dim3(8, 64), 256, 0, stream>>>(AO, Wob, bo, out);
}